// Round 2
// baseline (944.768 us; speedup 1.0000x reference)
//
#include <hip/hip_runtime.h>

#define NN 16384      // nodes
#define NE 262144     // edges
#define NSPEC 10
#define KC 64
#define MLPH 16

#define GEMM_BLOCKS 1024   // x4 waves = 4096 waves for the register-W GEMMs

__device__ __forceinline__ float wave_reduce(float v) {
#pragma unroll
    for (int off = 32; off > 0; off >>= 1) v += __shfl_down(v, off, 64);
    return v;
}

// feats[n][m][k]: m==0 -> W_embed[species[n]], else 0.  float4 over NN*9*16
__global__ void k_init_feats(const float* __restrict__ W_embed,
                             const int* __restrict__ species,
                             float4* __restrict__ feats4) {
    int tid = blockIdx.x * 256 + threadIdx.x;   // 0 .. NN*144-1
    int n = tid / 144;
    int rr = tid - n * 144;
    int m = rr >> 4;
    int q = rr & 15;
    float4 v = make_float4(0.f, 0.f, 0.f, 0.f);
    if (m == 0) {
        int sp = species[n];
        v = reinterpret_cast<const float4*>(W_embed + sp * KC)[q];
    }
    feats4[tid] = v;
}

__global__ void k_hist(const int* __restrict__ receivers, int* __restrict__ count) {
    int e = blockIdx.x * 256 + threadIdx.x;
    atomicAdd(&count[receivers[e]], 1);
}

__global__ void k_hist_sp(const int* __restrict__ species, int* __restrict__ sp_cnt) {
    int n = blockIdx.x * 256 + threadIdx.x;
    atomicAdd(&sp_cnt[species[n]], 1);
}

// exclusive scan of count[0..NN-1] -> row_start[0..NN]; also scans sp_cnt -> sp_start
__global__ void k_scan(const int* __restrict__ count, int* __restrict__ row_start,
                       const int* __restrict__ sp_cnt, int* __restrict__ sp_start) {
    __shared__ int lds[1024];
    int t = threadIdx.x;
    int base = t * 16;
    int local[16];
    int s = 0;
#pragma unroll
    for (int b = 0; b < 16; ++b) { local[b] = count[base + b]; s += local[b]; }
    lds[t] = s;
    __syncthreads();
    for (int off = 1; off < 1024; off <<= 1) {
        int v = (t >= off) ? lds[t - off] : 0;
        __syncthreads();
        lds[t] += v;
        __syncthreads();
    }
    int run = lds[t] - s;   // exclusive
#pragma unroll
    for (int b = 0; b < 16; ++b) { row_start[base + b] = run; run += local[b]; }
    if (t == 1023) row_start[NN] = run;
    if (t == 0) {
        int r2 = 0;
        for (int sp = 0; sp < NSPEC; ++sp) { sp_start[sp] = r2; r2 += sp_cnt[sp]; }
        sp_start[NSPEC] = r2;
    }
}

__global__ void k_scatter_sp(const int* __restrict__ species,
                             const int* __restrict__ sp_start,
                             int* __restrict__ sp_cursor,
                             int* __restrict__ ord) {
    int n = blockIdx.x * 256 + threadIdx.x;
    int sp = species[n];
    int pos = sp_start[sp] + atomicAdd(&sp_cursor[sp], 1);
    ord[pos] = n;
}

// per edge: geometry (Y 9, rad 8) written directly into receiver-sorted slot
__global__ void k_geom(const float* __restrict__ pos,
                       const float* __restrict__ shifts,
                       const int* __restrict__ senders,
                       const int* __restrict__ receivers,
                       const int* __restrict__ row_start,
                       int* __restrict__ cursor,
                       float* __restrict__ Ybuf,
                       float* __restrict__ radb,
                       int* __restrict__ ssort) {
    int e = blockIdx.x * 256 + threadIdx.x;
    int s = senders[e], r = receivers[e];
    float dx = pos[r * 3 + 0] - pos[s * 3 + 0] + shifts[e * 3 + 0];
    float dy = pos[r * 3 + 1] - pos[s * 3 + 1] + shifts[e * 3 + 1];
    float dz = pos[r * 3 + 2] - pos[s * 3 + 2] + shifts[e * 3 + 2];
    float rn = sqrtf(dx * dx + dy * dy + dz * dz);
    float den = (rn > 1e-9f) ? rn : 1.0f;
    float x = dx / den, y = dy / den, z = dz / den;
    const float s3  = 1.7320508075688772f;   // sqrt(3)
    const float s15 = 3.8729833462074170f;   // sqrt(15)
    const float s5h = 1.1180339887498949f;   // sqrt(5)/2
    const float s15h = 1.9364916731037085f;  // sqrt(15)/2
    int p = row_start[r] + atomicAdd(&cursor[r], 1);
    float* Yp = Ybuf + p * 9;
    Yp[0] = 1.0f;
    Yp[1] = s3 * x;
    Yp[2] = s3 * y;
    Yp[3] = s3 * z;
    Yp[4] = s15 * x * y;
    Yp[5] = s15 * y * z;
    Yp[6] = s5h * (3.0f * z * z - 1.0f);
    Yp[7] = s15 * x * z;
    Yp[8] = s15h * (x * x - y * y);
    float u = rn * 0.2f;   // r / R_MAX
    float env = 0.0f;
    if (u < 1.0f) {
        float u2 = u * u;
        float u5 = u2 * u2 * u;
        env = 1.0f - 21.0f * u5 + 35.0f * u5 * u - 15.0f * u5 * u2;
    }
    float pre = 0.63245553203367587f * env / den;   // sqrt(2/R_MAX)*env/r_safe
    float* rp = radb + p * 8;
#pragma unroll
    for (int nb = 1; nb <= 8; ++nb)
        rp[nb - 1] = pre * sinf((float)nb * 3.14159265358979323846f * u);
    ssort[p] = s;
}

// compact l=0 slice of feats into hs0 (NN*KC), float4 over NN*16
__global__ void k_hs0(const float4* __restrict__ feats4, float4* __restrict__ hs04) {
    int tid = blockIdx.x * 256 + threadIdx.x;
    int n = tid >> 4, q = tid & 15;
    hs04[tid] = feats4[n * 144 + q];
}

// one wave per node: A[n][m][k] = (1/16) * sum_edges hs[s][k]*Y[m]*R[l(m)][k]
__global__ void __launch_bounds__(256) k_aggregate(
    const float* __restrict__ hs0,
    const float* __restrict__ Ybuf,
    const float* __restrict__ radb,
    const int* __restrict__ ssort,
    const int* __restrict__ row_start,
    const float* __restrict__ Wr_i,    // W_rad + i*3*8*64, [l][b][k]
    float* __restrict__ A) {
    int wid = threadIdx.x >> 6;
    int lane = threadIdx.x & 63;
    int n = blockIdx.x * 4 + wid;
    float Wr[3][8];
#pragma unroll
    for (int l = 0; l < 3; ++l)
#pragma unroll
        for (int b = 0; b < 8; ++b) Wr[l][b] = Wr_i[(l * 8 + b) * 64 + lane];
    float acc[9];
#pragma unroll
    for (int m = 0; m < 9; ++m) acc[m] = 0.f;
    int e0 = row_start[n], e1 = row_start[n + 1];
    for (int e = e0; e < e1; ++e) {
        int s = ssort[e];
        float h = hs0[s * 64 + lane];
        const float* rp = radb + e * 8;
        float R0 = 0.f, R1 = 0.f, R2 = 0.f;
#pragma unroll
        for (int b = 0; b < 8; ++b) {
            float rb = rp[b];
            R0 += rb * Wr[0][b];
            R1 += rb * Wr[1][b];
            R2 += rb * Wr[2][b];
        }
        float t0 = h * R0, t1 = h * R1, t2 = h * R2;
        const float* Yp = Ybuf + e * 9;
        acc[0] += t0 * Yp[0];
        acc[1] += t1 * Yp[1];
        acc[2] += t1 * Yp[2];
        acc[3] += t1 * Yp[3];
        acc[4] += t2 * Yp[4];
        acc[5] += t2 * Yp[5];
        acc[6] += t2 * Yp[6];
        acc[7] += t2 * Yp[7];
        acc[8] += t2 * Yp[8];
    }
    const float inv_avg = 1.0f / 16.0f;
#pragma unroll
    for (int m = 0; m < 9; ++m) A[n * 576 + m * 64 + lane] = acc[m] * inv_avg;
}

// register-W GEMM: A[n][m][:] <- A[n][m][:] @ W_mix[l(m)], rows grouped by l
__global__ void __launch_bounds__(256) k_mix_gemm(float* A,
                                                  const float* __restrict__ Wm_i) {
    const int R = NN * 9;
    const int NWAVE = GEMM_BLOCKS * 4;
    int wgid = blockIdx.x * 4 + (threadIdx.x >> 6);
    int lane = threadIdx.x & 63;
    const int chunk = (R + NWAVE - 1) / NWAVE;
    int r0 = wgid * chunk;
    int r1 = r0 + chunk; if (r1 > R) r1 = R;
    if (r0 >= r1) return;
    float Wreg[64];
    int cur_l = -1;
    for (int r = r0; r < r1; ++r) {
        int l, n, m;
        if (r < NN)          { l = 0; n = r; m = 0; }
        else if (r < 4 * NN) { int q = r - NN;     l = 1; n = q / 3; m = 1 + q % 3; }
        else                 { int q = r - 4 * NN; l = 2; n = q / 5; m = 4 + q % 5; }
        if (l != cur_l) {
            cur_l = l;
            const float* Wp = Wm_i + l * 4096;
#pragma unroll
            for (int k = 0; k < 64; ++k) Wreg[k] = Wp[k * 64 + lane];
        }
        float* row = A + ((size_t)n * 9 + m) * 64;
        const float4* X4 = (const float4*)row;
        float acc0 = 0.f, acc1 = 0.f, acc2 = 0.f, acc3 = 0.f;
#pragma unroll
        for (int kk = 0; kk < 16; ++kk) {
            float4 xv = X4[kk];
            int k0 = kk * 4;
            acc0 += xv.x * Wreg[k0 + 0];
            acc1 += xv.y * Wreg[k0 + 1];
            acc2 += xv.z * Wreg[k0 + 2];
            acc3 += xv.w * Wreg[k0 + 3];
        }
        row[lane] = (acc0 + acc1) + (acc2 + acc3);   // all loads drained (deps) before store
    }
}

// per node: B = A*(w1+w2*A0+w3*inv), written back INTO A (in place)
__global__ void __launch_bounds__(256) k_prod(float* A,
                                              const float* __restrict__ Wp_i) {
    int wid = threadIdx.x >> 6;
    int lane = threadIdx.x & 63;
    int n = blockIdx.x * 4 + wid;
    float a[9];
#pragma unroll
    for (int m = 0; m < 9; ++m) a[m] = A[n * 576 + m * 64 + lane];
    float A0 = a[0];
    float inv = 0.f;
#pragma unroll
    for (int m = 0; m < 9; ++m) inv += a[m] * a[m];
    float w1[3], w2[3], w3[3];
#pragma unroll
    for (int l = 0; l < 3; ++l) {
        w1[l] = Wp_i[(0 * 3 + l) * 64 + lane];
        w2[l] = Wp_i[(1 * 3 + l) * 64 + lane];
        w3[l] = Wp_i[(2 * 3 + l) * 64 + lane];
    }
#pragma unroll
    for (int m = 0; m < 9; ++m) {
        int l = (m == 0) ? 0 : ((m < 4) ? 1 : 2);
        A[n * 576 + m * 64 + lane] = a[m] * (w1[l] + w2[l] * A0 + w3[l] * inv);
    }
}

// register-W GEMM over species-sorted rows:
// feats[n][m][:] = Bbuf[n][m][:] + feats[n][m][:] @ W_sc[sp(n)][l(m)]
// energy epilogue fused on l==0 rows.
template <int ITER>
__global__ void __launch_bounds__(256) k_sc_gemm(
    float* feats,
    const float* __restrict__ Bbuf,     // = A (holds B after k_prod)
    const int* __restrict__ ord,
    const int* __restrict__ sp_start,   // [NSPEC+1]
    const float* __restrict__ Wsc_i,    // W_sc + i*NSPEC*3*64*64
    const float* __restrict__ W_ro0,
    const float* __restrict__ W_m1,
    const float* __restrict__ b_m1,
    const float* __restrict__ W_m2,
    float* __restrict__ out) {
    const int R = NN * 9;
    const int NWAVE = GEMM_BLOCKS * 4;
    int wgid = blockIdx.x * 4 + (threadIdx.x >> 6);
    int lane = threadIdx.x & 63;
    const int chunk = (R + NWAVE - 1) / NWAVE;
    int r0 = wgid * chunk;
    int r1 = r0 + chunk; if (r1 > R) r1 = R;
    if (r0 >= r1) return;

    int s = 0;
    while (s < NSPEC - 1 && r0 >= 9 * sp_start[s + 1]) ++s;
    float Wreg[64];
    int cur_l = -1, cur_s = -1;

    for (int r = r0; r < r1; ++r) {
        while (s < NSPEC - 1 && r >= 9 * sp_start[s + 1]) ++s;
        int base = sp_start[s];
        int cnt  = sp_start[s + 1] - base;
        int q = r - 9 * base;
        int l, m, pos;
        if (q < cnt)          { l = 0; m = 0; pos = q; }
        else if (q < 4 * cnt) { int t = q - cnt;     l = 1; m = 1 + t % 3; pos = t / 3; }
        else                  { int t = q - 4 * cnt; l = 2; m = 4 + t % 5; pos = t / 5; }
        int node = ord[base + pos];

        if (l != cur_l || s != cur_s) {
            cur_l = l; cur_s = s;
            const float* Wp = Wsc_i + ((size_t)s * 3 + l) * 4096;
#pragma unroll
            for (int k = 0; k < 64; ++k) Wreg[k] = Wp[k * 64 + lane];
        }

        float* row = feats + ((size_t)node * 9 + m) * 64;
        const float4* X4 = (const float4*)row;
        float acc0 = 0.f, acc1 = 0.f, acc2 = 0.f, acc3 = 0.f;
#pragma unroll
        for (int kk = 0; kk < 16; ++kk) {
            float4 xv = X4[kk];
            int k0 = kk * 4;
            acc0 += xv.x * Wreg[k0 + 0];
            acc1 += xv.y * Wreg[k0 + 1];
            acc2 += xv.z * Wreg[k0 + 2];
            acc3 += xv.w * Wreg[k0 + 3];
        }
        float outv = (acc0 + acc1) + (acc2 + acc3)
                   + Bbuf[((size_t)node * 9 + m) * 64 + lane];
        row[lane] = outv;

        if (l == 0) {   // wave-uniform: r-derived
            if (ITER == 0) {
                float e = wave_reduce(outv * W_ro0[lane]);
                if (lane == 0) out[2 * node + 0] = e;
            } else {
                int h = lane & 15;
                float t = b_m1[h];
#pragma unroll
                for (int k = 0; k < 64; ++k)
                    t += __shfl(outv, k, 64) * W_m1[k * MLPH + h];
                float sig = 1.0f / (1.0f + expf(-t));
                float contrib = (lane < MLPH) ? t * sig * W_m2[lane] : 0.f;
                float e = wave_reduce(contrib);
                if (lane == 0) out[2 * node + 1] = e;
            }
        }
    }
}

extern "C" void kernel_launch(void* const* d_in, const int* in_sizes, int n_in,
                              void* d_out, int out_size, void* d_ws, size_t ws_size,
                              hipStream_t stream) {
    const float* positions = (const float*)d_in[0];
    const float* shifts    = (const float*)d_in[1];
    const int*   species   = (const int*)d_in[2];
    const int*   senders   = (const int*)d_in[3];
    const int*   receivers = (const int*)d_in[4];
    const float* W_embed   = (const float*)d_in[5];
    const float* W_rad     = (const float*)d_in[6];
    const float* W_mix     = (const float*)d_in[7];
    const float* W_prod    = (const float*)d_in[8];
    const float* W_sc      = (const float*)d_in[9];
    const float* W_ro0     = (const float*)d_in[10];
    const float* W_m1      = (const float*)d_in[11];
    const float* b_m1      = (const float*)d_in[12];
    const float* W_m2      = (const float*)d_in[13];
    float* out = (float*)d_out;

    char* p = (char*)d_ws;
    float* feats = (float*)p; p += (size_t)NN * 576 * 4;   // 37.75 MB
    float* A     = (float*)p; p += (size_t)NN * 576 * 4;   // 37.75 MB
    float* Ybuf  = (float*)p; p += (size_t)NE * 9 * 4;     //  9.44 MB
    float* radb  = (float*)p; p += (size_t)NE * 8 * 4;     //  8.39 MB
    float* hs0   = (float*)p; p += (size_t)NN * KC * 4;    //  4.19 MB
    int* ssort     = (int*)p; p += (size_t)NE * 4;         //  1.05 MB
    int* ord       = (int*)p; p += (size_t)NN * 4;
    int* count     = (int*)p; p += (size_t)NN * 4;         // --- memset region start
    int* cursor    = (int*)p; p += (size_t)NN * 4;
    int* sp_cnt    = (int*)p; p += 16 * 4;
    int* sp_cursor = (int*)p; p += 16 * 4;                 // --- memset region end
    int* row_start = (int*)p; p += (size_t)(NN + 1) * 4;
    int* sp_start  = (int*)p; p += 16 * 4;

    hipMemsetAsync(count, 0, ((size_t)2 * NN + 32) * 4, stream);

    k_init_feats<<<NN * 144 / 256, 256, 0, stream>>>(W_embed, species, (float4*)feats);
    k_hist<<<NE / 256, 256, 0, stream>>>(receivers, count);
    k_hist_sp<<<NN / 256, 256, 0, stream>>>(species, sp_cnt);
    k_scan<<<1, 1024, 0, stream>>>(count, row_start, sp_cnt, sp_start);
    k_geom<<<NE / 256, 256, 0, stream>>>(positions, shifts, senders, receivers,
                                         row_start, cursor, Ybuf, radb, ssort);
    k_scatter_sp<<<NN / 256, 256, 0, stream>>>(species, sp_start, sp_cursor, ord);

    for (int i = 0; i < 2; ++i) {
        k_hs0<<<NN * 16 / 256, 256, 0, stream>>>((const float4*)feats, (float4*)hs0);
        k_aggregate<<<NN / 4, 256, 0, stream>>>(hs0, Ybuf, radb, ssort, row_start,
                                                W_rad + (size_t)i * 3 * 8 * 64, A);
        k_mix_gemm<<<GEMM_BLOCKS, 256, 0, stream>>>(A, W_mix + (size_t)i * 3 * 64 * 64);
        k_prod<<<NN / 4, 256, 0, stream>>>(A, W_prod + (size_t)i * 3 * 3 * 64);
        if (i == 0)
            k_sc_gemm<0><<<GEMM_BLOCKS, 256, 0, stream>>>(feats, A, ord, sp_start,
                W_sc + 0, W_ro0, W_m1, b_m1, W_m2, out);
        else
            k_sc_gemm<1><<<GEMM_BLOCKS, 256, 0, stream>>>(feats, A, ord, sp_start,
                W_sc + (size_t)NSPEC * 3 * 64 * 64, W_ro0, W_m1, b_m1, W_m2, out);
    }
}

// Round 3
// 658.454 us; speedup vs baseline: 1.4348x; 1.4348x over previous
//
#include <hip/hip_runtime.h>

#define NN 16384      // nodes
#define NE 262144     // edges
#define NSPEC 10
#define KC 64
#define MLPH 16

__device__ __forceinline__ float wave_reduce(float v) {
#pragma unroll
    for (int off = 32; off > 0; off >>= 1) v += __shfl_down(v, off, 64);
    return v;
}

__device__ __forceinline__ float f4c(const float4& v, int j) {
    const float* p = &v.x;   // j is compile-time after unroll -> extractelement
    return p[j];
}

// h0[n][k] = W_embed[species[n]][k]   (float4 over NN*16)
__global__ void k_init_h0(const float* __restrict__ W_embed,
                          const int* __restrict__ species,
                          float4* __restrict__ h04) {
    int tid = blockIdx.x * 256 + threadIdx.x;
    int n = tid >> 4, q = tid & 15;
    h04[tid] = reinterpret_cast<const float4*>(W_embed + species[n] * KC)[q];
}

__global__ void k_hist(const int* __restrict__ receivers, int* __restrict__ count) {
    int e = blockIdx.x * 256 + threadIdx.x;
    atomicAdd(&count[receivers[e]], 1);
}

__global__ void k_hist_sp(const int* __restrict__ species, int* __restrict__ sp_cnt) {
    int n = blockIdx.x * 256 + threadIdx.x;
    atomicAdd(&sp_cnt[species[n]], 1);
}

// exclusive scan of count -> row_start; also sp_cnt -> sp_start
__global__ void k_scan(const int* __restrict__ count, int* __restrict__ row_start,
                       const int* __restrict__ sp_cnt, int* __restrict__ sp_start) {
    __shared__ int lds[1024];
    int t = threadIdx.x;
    int base = t * 16;
    int local[16];
    int s = 0;
#pragma unroll
    for (int b = 0; b < 16; ++b) { local[b] = count[base + b]; s += local[b]; }
    lds[t] = s;
    __syncthreads();
    for (int off = 1; off < 1024; off <<= 1) {
        int v = (t >= off) ? lds[t - off] : 0;
        __syncthreads();
        lds[t] += v;
        __syncthreads();
    }
    int run = lds[t] - s;
#pragma unroll
    for (int b = 0; b < 16; ++b) { row_start[base + b] = run; run += local[b]; }
    if (t == 1023) row_start[NN] = run;
    if (t == 0) {
        int r2 = 0;
        for (int sp = 0; sp < NSPEC; ++sp) { sp_start[sp] = r2; r2 += sp_cnt[sp]; }
        sp_start[NSPEC] = r2;
    }
}

__global__ void k_scatter_sp(const int* __restrict__ species,
                             const int* __restrict__ sp_start,
                             int* __restrict__ sp_cursor,
                             int* __restrict__ ord) {
    int n = blockIdx.x * 256 + threadIdx.x;
    int sp = species[n];
    int pos = sp_start[sp] + atomicAdd(&sp_cursor[sp], 1);
    ord[pos] = n;
}

// per edge: geometry written into receiver-sorted slot
__global__ void k_geom(const float* __restrict__ pos,
                       const float* __restrict__ shifts,
                       const int* __restrict__ senders,
                       const int* __restrict__ receivers,
                       const int* __restrict__ row_start,
                       int* __restrict__ cursor,
                       float* __restrict__ Ybuf,
                       float* __restrict__ radb,
                       int* __restrict__ ssort) {
    int e = blockIdx.x * 256 + threadIdx.x;
    int s = senders[e], r = receivers[e];
    float dx = pos[r * 3 + 0] - pos[s * 3 + 0] + shifts[e * 3 + 0];
    float dy = pos[r * 3 + 1] - pos[s * 3 + 1] + shifts[e * 3 + 1];
    float dz = pos[r * 3 + 2] - pos[s * 3 + 2] + shifts[e * 3 + 2];
    float rn = sqrtf(dx * dx + dy * dy + dz * dz);
    float den = (rn > 1e-9f) ? rn : 1.0f;
    float x = dx / den, y = dy / den, z = dz / den;
    const float s3  = 1.7320508075688772f;
    const float s15 = 3.8729833462074170f;
    const float s5h = 1.1180339887498949f;
    const float s15h = 1.9364916731037085f;
    int p = row_start[r] + atomicAdd(&cursor[r], 1);
    float* Yp = Ybuf + p * 9;
    Yp[0] = 1.0f;
    Yp[1] = s3 * x;
    Yp[2] = s3 * y;
    Yp[3] = s3 * z;
    Yp[4] = s15 * x * y;
    Yp[5] = s15 * y * z;
    Yp[6] = s5h * (3.0f * z * z - 1.0f);
    Yp[7] = s15 * x * z;
    Yp[8] = s15h * (x * x - y * y);
    float u = rn * 0.2f;
    float env = 0.0f;
    if (u < 1.0f) {
        float u2 = u * u;
        float u5 = u2 * u2 * u;
        env = 1.0f - 21.0f * u5 + 35.0f * u5 * u - 15.0f * u5 * u2;
    }
    float pre = 0.63245553203367587f * env / den;
    float* rp = radb + p * 8;
#pragma unroll
    for (int nb = 1; nb <= 8; ++nb)
        rp[nb - 1] = pre * sinf((float)nb * 3.14159265358979323846f * u);
    ssort[p] = s;
}

// one wave per node: A[n][m][k] = (1/16) * sum_edges h[s][k]*Y[m]*R[l(m)][k]
__global__ void __launch_bounds__(256) k_aggregate(
    const float* __restrict__ h,
    const float* __restrict__ Ybuf,
    const float* __restrict__ radb,
    const int* __restrict__ ssort,
    const int* __restrict__ row_start,
    const float* __restrict__ Wr_i,    // [l][b][k]
    float* __restrict__ A) {
    int wid = threadIdx.x >> 6;
    int lane = threadIdx.x & 63;
    int n = blockIdx.x * 4 + wid;
    float Wr[3][8];
#pragma unroll
    for (int l = 0; l < 3; ++l)
#pragma unroll
        for (int b = 0; b < 8; ++b) Wr[l][b] = Wr_i[(l * 8 + b) * 64 + lane];
    float acc[9];
#pragma unroll
    for (int m = 0; m < 9; ++m) acc[m] = 0.f;
    int e0 = row_start[n], e1 = row_start[n + 1];
    for (int e = e0; e < e1; ++e) {
        int s = ssort[e];
        float hv = h[s * 64 + lane];
        const float* rp = radb + e * 8;
        float R0 = 0.f, R1 = 0.f, R2 = 0.f;
#pragma unroll
        for (int b = 0; b < 8; ++b) {
            float rb = rp[b];
            R0 += rb * Wr[0][b];
            R1 += rb * Wr[1][b];
            R2 += rb * Wr[2][b];
        }
        float t0 = hv * R0, t1 = hv * R1, t2 = hv * R2;
        const float* Yp = Ybuf + e * 9;
        acc[0] += t0 * Yp[0];
        acc[1] += t1 * Yp[1];
        acc[2] += t1 * Yp[2];
        acc[3] += t1 * Yp[3];
        acc[4] += t2 * Yp[4];
        acc[5] += t2 * Yp[5];
        acc[6] += t2 * Yp[6];
        acc[7] += t2 * Yp[7];
        acc[8] += t2 * Yp[8];
    }
    const float inv_avg = 1.0f / 16.0f;
#pragma unroll
    for (int m = 0; m < 9; ++m) A[(size_t)n * 576 + m * 64 + lane] = acc[m] * inv_avg;
}

// node-partitioned mix + fused prod: Bout[n][m][:] = prod(mix(A[n]))
// all 3 W_mix staged in LDS (48 KB); 8 nodes per wave; out-of-place.
__global__ void __launch_bounds__(256) k_mixprod(
    const float* __restrict__ A,
    float* __restrict__ Bout,
    const float* __restrict__ Wm_i,    // 3*64*64
    const float* __restrict__ Wp_i) {  // [3][3][64]
    __shared__ float Wlds[3 * 4096];
    {
        float4* Wl4 = (float4*)Wlds;
        const float4* W4 = (const float4*)Wm_i;
#pragma unroll
        for (int i = 0; i < 12; ++i)
            Wl4[threadIdx.x + 256 * i] = W4[threadIdx.x + 256 * i];
    }
    __syncthreads();
    int lane = threadIdx.x & 63;
    int wid = threadIdx.x >> 6;
    float w1[3], w2[3], w3[3];
#pragma unroll
    for (int l = 0; l < 3; ++l) {
        w1[l] = Wp_i[(0 * 3 + l) * 64 + lane];
        w2[l] = Wp_i[(1 * 3 + l) * 64 + lane];
        w3[l] = Wp_i[(2 * 3 + l) * 64 + lane];
    }
    int n = blockIdx.x * 32 + wid * 8;
    for (int it = 0; it < 8; ++it, ++n) {
        const float* Arow = A + (size_t)n * 576;
        float acc[9];
#pragma unroll
        for (int m = 0; m < 9; ++m) acc[m] = 0.f;
#pragma unroll
        for (int c4 = 0; c4 < 16; ++c4) {
            float4 xv[9];
#pragma unroll
            for (int m = 0; m < 9; ++m)
                xv[m] = reinterpret_cast<const float4*>(Arow + m * 64)[c4];
#pragma unroll
            for (int j = 0; j < 4; ++j) {
                int k = c4 * 4 + j;
                float wv0 = Wlds[k * 64 + lane];
                float wv1 = Wlds[4096 + k * 64 + lane];
                float wv2 = Wlds[8192 + k * 64 + lane];
                acc[0] += f4c(xv[0], j) * wv0;
                acc[1] += f4c(xv[1], j) * wv1;
                acc[2] += f4c(xv[2], j) * wv1;
                acc[3] += f4c(xv[3], j) * wv1;
                acc[4] += f4c(xv[4], j) * wv2;
                acc[5] += f4c(xv[5], j) * wv2;
                acc[6] += f4c(xv[6], j) * wv2;
                acc[7] += f4c(xv[7], j) * wv2;
                acc[8] += f4c(xv[8], j) * wv2;
            }
        }
        float A0 = acc[0];
        float inv = 0.f;
#pragma unroll
        for (int m = 0; m < 9; ++m) inv += acc[m] * acc[m];
        float* Brow = Bout + (size_t)n * 576;
#pragma unroll
        for (int m = 0; m < 9; ++m) {
            int l = (m == 0) ? 0 : ((m < 4) ? 1 : 2);
            Brow[m * 64 + lane] = acc[m] * (w1[l] + w2[l] * A0 + w3[l] * inv);
        }
    }
}

// l=0 self-connection GEMM over species-sorted nodes + energy epilogue.
// ITER 0: h_out = B0 + h_in @ Wsc[sp,0];  e0 = h_out . W_ro0
// ITER 1: f0    = B0 + h_in @ Wsc[sp,0];  e1 = silu(f0 @ W_m1 + b) @ W_m2 (no store)
#define RPB 32           // rows (nodes) per block
template <int ITER>
__global__ void __launch_bounds__(256) k_sc(
    const float* __restrict__ h_in,
    const float* __restrict__ Bbuf,      // Amix, stride 576, m=0 plane
    float* __restrict__ h_out,
    const int* __restrict__ ord,
    const int* __restrict__ sp_start,
    const float* __restrict__ Wsc_i,     // + sp*3*4096 selects l=0 plane
    const float* __restrict__ W_ro0,
    const float* __restrict__ W_m1,
    const float* __restrict__ b_m1,
    const float* __restrict__ W_m2,
    float* __restrict__ out) {
    const int BPS = NN / RPB;
    int sp = blockIdx.x / BPS;
    int c  = blockIdx.x - sp * BPS;
    int base = sp_start[sp];
    int cnt  = sp_start[sp + 1] - base;
    int r0 = c * RPB;
    if (r0 >= cnt) return;
    __shared__ float Wlds[4096];
    {
        const float4* W4 = (const float4*)(Wsc_i + (size_t)sp * 3 * 4096);
        float4* Wl4 = (float4*)Wlds;
#pragma unroll
        for (int i = 0; i < 4; ++i)
            Wl4[threadIdx.x + 256 * i] = W4[threadIdx.x + 256 * i];
    }
    __syncthreads();
    int lane = threadIdx.x & 63;
    int wid = threadIdx.x >> 6;
    float wro = W_ro0[lane];
    int rend = min(r0 + RPB, cnt);
    for (int q = r0 + wid * 4; q < rend; q += 16) {
        int nd[4];
#pragma unroll
        for (int t = 0; t < 4; ++t)
            nd[t] = ord[base + min(q + t, rend - 1)];
        float acc[4] = {0.f, 0.f, 0.f, 0.f};
#pragma unroll
        for (int c4 = 0; c4 < 16; ++c4) {
            float4 xv[4];
#pragma unroll
            for (int t = 0; t < 4; ++t)
                xv[t] = reinterpret_cast<const float4*>(h_in + (size_t)nd[t] * 64)[c4];
#pragma unroll
            for (int j = 0; j < 4; ++j) {
                float wv = Wlds[(c4 * 4 + j) * 64 + lane];
                acc[0] += f4c(xv[0], j) * wv;
                acc[1] += f4c(xv[1], j) * wv;
                acc[2] += f4c(xv[2], j) * wv;
                acc[3] += f4c(xv[3], j) * wv;
            }
        }
#pragma unroll
        for (int t = 0; t < 4; ++t) {
            if (q + t >= rend) break;
            int node = nd[t];
            float outv = acc[t] + Bbuf[(size_t)node * 576 + lane];
            if (ITER == 0) {
                h_out[(size_t)node * 64 + lane] = outv;
                float e = wave_reduce(outv * wro);
                if (lane == 0) out[2 * node + 0] = e;
            } else {
                int hh = lane & 15;
                float tacc = b_m1[hh];
#pragma unroll
                for (int k = 0; k < 64; ++k)
                    tacc += __shfl(outv, k, 64) * W_m1[k * MLPH + hh];
                float sig = 1.0f / (1.0f + expf(-tacc));
                float contrib = (lane < MLPH) ? tacc * sig * W_m2[lane] : 0.f;
                float e = wave_reduce(contrib);
                if (lane == 0) out[2 * node + 1] = e;
            }
        }
    }
}

extern "C" void kernel_launch(void* const* d_in, const int* in_sizes, int n_in,
                              void* d_out, int out_size, void* d_ws, size_t ws_size,
                              hipStream_t stream) {
    const float* positions = (const float*)d_in[0];
    const float* shifts    = (const float*)d_in[1];
    const int*   species   = (const int*)d_in[2];
    const int*   senders   = (const int*)d_in[3];
    const int*   receivers = (const int*)d_in[4];
    const float* W_embed   = (const float*)d_in[5];
    const float* W_rad     = (const float*)d_in[6];
    const float* W_mix     = (const float*)d_in[7];
    const float* W_prod    = (const float*)d_in[8];
    const float* W_sc      = (const float*)d_in[9];
    const float* W_ro0     = (const float*)d_in[10];
    const float* W_m1      = (const float*)d_in[11];
    const float* b_m1      = (const float*)d_in[12];
    const float* W_m2      = (const float*)d_in[13];
    float* out = (float*)d_out;

    char* p = (char*)d_ws;
    float* A    = (float*)p; p += (size_t)NN * 576 * 4;   // 37.75 MB
    float* Amix = (float*)p; p += (size_t)NN * 576 * 4;   // 37.75 MB
    float* Ybuf = (float*)p; p += (size_t)NE * 9 * 4;     //  9.44 MB
    float* radb = (float*)p; p += (size_t)NE * 8 * 4;     //  8.39 MB
    float* h0   = (float*)p; p += (size_t)NN * KC * 4;    //  4.19 MB
    float* h1   = (float*)p; p += (size_t)NN * KC * 4;    //  4.19 MB
    int* ssort     = (int*)p; p += (size_t)NE * 4;        //  1.05 MB
    int* ord       = (int*)p; p += (size_t)NN * 4;
    int* count     = (int*)p; p += (size_t)NN * 4;        // memset region start
    int* cursor    = (int*)p; p += (size_t)NN * 4;
    int* sp_cnt    = (int*)p; p += 16 * 4;
    int* sp_cursor = (int*)p; p += 16 * 4;                // memset region end
    int* row_start = (int*)p; p += (size_t)(NN + 1) * 4;
    int* sp_start  = (int*)p; p += 16 * 4;

    hipMemsetAsync(count, 0, ((size_t)2 * NN + 32) * 4, stream);

    k_init_h0<<<NN * 16 / 256, 256, 0, stream>>>(W_embed, species, (float4*)h0);
    k_hist<<<NE / 256, 256, 0, stream>>>(receivers, count);
    k_hist_sp<<<NN / 256, 256, 0, stream>>>(species, sp_cnt);
    k_scan<<<1, 1024, 0, stream>>>(count, row_start, sp_cnt, sp_start);
    k_geom<<<NE / 256, 256, 0, stream>>>(positions, shifts, senders, receivers,
                                         row_start, cursor, Ybuf, radb, ssort);
    k_scatter_sp<<<NN / 256, 256, 0, stream>>>(species, sp_start, sp_cursor, ord);

    // ---- iteration 0 ----
    k_aggregate<<<NN / 4, 256, 0, stream>>>(h0, Ybuf, radb, ssort, row_start,
                                            W_rad + 0, A);
    k_mixprod<<<NN / 32, 256, 0, stream>>>(A, Amix, W_mix + 0, W_prod + 0);
    k_sc<0><<<NSPEC * (NN / RPB), 256, 0, stream>>>(h0, Amix, h1, ord, sp_start,
        W_sc + 0, W_ro0, W_m1, b_m1, W_m2, out);

    // ---- iteration 1 ----
    k_aggregate<<<NN / 4, 256, 0, stream>>>(h1, Ybuf, radb, ssort, row_start,
                                            W_rad + 3 * 8 * 64, A);
    k_mixprod<<<NN / 32, 256, 0, stream>>>(A, Amix, W_mix + 3 * 4096,
                                           W_prod + 3 * 3 * 64);
    k_sc<1><<<NSPEC * (NN / RPB), 256, 0, stream>>>(h1, Amix, h0 /*unused*/, ord,
        sp_start, W_sc + (size_t)NSPEC * 3 * 4096, W_ro0, W_m1, b_m1, W_m2, out);
}

// Round 4
// 477.639 us; speedup vs baseline: 1.9780x; 1.3786x over previous
//
#include <hip/hip_runtime.h>

#define NN 16384      // nodes
#define NE 262144     // edges
#define NSPEC 10
#define KC 64
#define MLPH 16

__device__ __forceinline__ float wave_reduce(float v) {
#pragma unroll
    for (int off = 32; off > 0; off >>= 1) v += __shfl_down(v, off, 64);
    return v;
}

__device__ __forceinline__ float f4c(const float4& v, int j) {
    const float* p = &v.x;   // j compile-time after unroll
    return p[j];
}

// h0[n][k] = W_embed[species[n]][k]
__global__ void k_init_h0(const float* __restrict__ W_embed,
                          const int* __restrict__ species,
                          float4* __restrict__ h04) {
    int tid = blockIdx.x * 256 + threadIdx.x;
    int n = tid >> 4, q = tid & 15;
    h04[tid] = reinterpret_cast<const float4*>(W_embed + species[n] * KC)[q];
}

__global__ void k_hist(const int* __restrict__ receivers, int* __restrict__ count) {
    int e = blockIdx.x * 256 + threadIdx.x;
    atomicAdd(&count[receivers[e]], 1);
}

__global__ void k_hist_sp(const int* __restrict__ species, int* __restrict__ sp_cnt) {
    int n = blockIdx.x * 256 + threadIdx.x;
    atomicAdd(&sp_cnt[species[n]], 1);
}

__global__ void k_scan(const int* __restrict__ count, int* __restrict__ row_start,
                       const int* __restrict__ sp_cnt, int* __restrict__ sp_start) {
    __shared__ int lds[1024];
    int t = threadIdx.x;
    int base = t * 16;
    int local[16];
    int s = 0;
#pragma unroll
    for (int b = 0; b < 16; ++b) { local[b] = count[base + b]; s += local[b]; }
    lds[t] = s;
    __syncthreads();
    for (int off = 1; off < 1024; off <<= 1) {
        int v = (t >= off) ? lds[t - off] : 0;
        __syncthreads();
        lds[t] += v;
        __syncthreads();
    }
    int run = lds[t] - s;
#pragma unroll
    for (int b = 0; b < 16; ++b) { row_start[base + b] = run; run += local[b]; }
    if (t == 1023) row_start[NN] = run;
    if (t == 0) {
        int r2 = 0;
        for (int sp = 0; sp < NSPEC; ++sp) { sp_start[sp] = r2; r2 += sp_cnt[sp]; }
        sp_start[NSPEC] = r2;
    }
}

__global__ void k_scatter_sp(const int* __restrict__ species,
                             const int* __restrict__ sp_start,
                             int* __restrict__ sp_cursor,
                             int* __restrict__ ord) {
    int n = blockIdx.x * 256 + threadIdx.x;
    int sp = species[n];
    int pos = sp_start[sp] + atomicAdd(&sp_cursor[sp], 1);
    ord[pos] = n;
}

// per edge: packed 20-float record written into receiver-sorted slot
// rec = [Y0..Y8, rad0..rad7, s_bits, pad, pad]
__global__ void k_geom(const float* __restrict__ pos,
                       const float* __restrict__ shifts,
                       const int* __restrict__ senders,
                       const int* __restrict__ receivers,
                       const int* __restrict__ row_start,
                       int* __restrict__ cursor,
                       float* __restrict__ edgerec) {
    int e = blockIdx.x * 256 + threadIdx.x;
    int s = senders[e], r = receivers[e];
    float dx = pos[r * 3 + 0] - pos[s * 3 + 0] + shifts[e * 3 + 0];
    float dy = pos[r * 3 + 1] - pos[s * 3 + 1] + shifts[e * 3 + 1];
    float dz = pos[r * 3 + 2] - pos[s * 3 + 2] + shifts[e * 3 + 2];
    float rn = sqrtf(dx * dx + dy * dy + dz * dz);
    float den = (rn > 1e-9f) ? rn : 1.0f;
    float x = dx / den, y = dy / den, z = dz / den;
    const float s3  = 1.7320508075688772f;
    const float s15 = 3.8729833462074170f;
    const float s5h = 1.1180339887498949f;
    const float s15h = 1.9364916731037085f;
    float rec[20];
    rec[0] = 1.0f;
    rec[1] = s3 * x;
    rec[2] = s3 * y;
    rec[3] = s3 * z;
    rec[4] = s15 * x * y;
    rec[5] = s15 * y * z;
    rec[6] = s5h * (3.0f * z * z - 1.0f);
    rec[7] = s15 * x * z;
    rec[8] = s15h * (x * x - y * y);
    float u = rn * 0.2f;
    float env = 0.0f;
    if (u < 1.0f) {
        float u2 = u * u;
        float u5 = u2 * u2 * u;
        env = 1.0f - 21.0f * u5 + 35.0f * u5 * u - 15.0f * u5 * u2;
    }
    float pre = 0.63245553203367587f * env / den;
#pragma unroll
    for (int nb = 1; nb <= 8; ++nb)
        rec[8 + nb] = pre * sinf((float)nb * 3.14159265358979323846f * u);
    rec[17] = __int_as_float(s);
    rec[18] = 0.f; rec[19] = 0.f;
    int p = row_start[r] + atomicAdd(&cursor[r], 1);
    float4* o = (float4*)(edgerec + (size_t)p * 20);
#pragma unroll
    for (int i = 0; i < 5; ++i)
        o[i] = make_float4(rec[4 * i], rec[4 * i + 1], rec[4 * i + 2], rec[4 * i + 3]);
}

__device__ __forceinline__ void agg_edge(
    const float4& a0, const float4& a1, const float4& a2,
    const float4& a3, const float4& a4, float hv,
    const float (&Wr)[3][8], float (&acc)[9]) {
    float rad[8] = {a2.y, a2.z, a2.w, a3.x, a3.y, a3.z, a3.w, a4.x};
    float R0 = 0.f, R1 = 0.f, R2 = 0.f;
#pragma unroll
    for (int b = 0; b < 8; ++b) {
        R0 += rad[b] * Wr[0][b];
        R1 += rad[b] * Wr[1][b];
        R2 += rad[b] * Wr[2][b];
    }
    float t0 = hv * R0, t1 = hv * R1, t2 = hv * R2;
    acc[0] += t0 * a0.x;
    acc[1] += t1 * a0.y;
    acc[2] += t1 * a0.z;
    acc[3] += t1 * a0.w;
    acc[4] += t2 * a1.x;
    acc[5] += t2 * a1.y;
    acc[6] += t2 * a1.z;
    acc[7] += t2 * a1.w;
    acc[8] += t2 * a2.x;
}

// one wave per node
__global__ void __launch_bounds__(256) k_aggregate(
    const float* __restrict__ h,
    const float* __restrict__ edgerec,
    const int* __restrict__ row_start,
    const float* __restrict__ Wr_i,    // [l][b][k]
    float* __restrict__ A) {
    int wid = threadIdx.x >> 6;
    int lane = threadIdx.x & 63;
    int n = blockIdx.x * 4 + wid;
    float Wr[3][8];
#pragma unroll
    for (int l = 0; l < 3; ++l)
#pragma unroll
        for (int b = 0; b < 8; ++b) Wr[l][b] = Wr_i[(l * 8 + b) * 64 + lane];
    float acc[9];
#pragma unroll
    for (int m = 0; m < 9; ++m) acc[m] = 0.f;
    int e0 = row_start[n], e1 = row_start[n + 1];
    int e = e0;
    for (; e + 2 <= e1; e += 2) {
        const float4* ra = (const float4*)(edgerec + (size_t)e * 20);
        float4 a0 = ra[0], a1 = ra[1], a2 = ra[2], a3 = ra[3], a4 = ra[4];
        float4 b0 = ra[5], b1 = ra[6], b2 = ra[7], b3 = ra[8], b4 = ra[9];
        int sa = __float_as_int(a4.y);
        int sb = __float_as_int(b4.y);
        float ha = h[(size_t)sa * 64 + lane];
        float hb = h[(size_t)sb * 64 + lane];
        agg_edge(a0, a1, a2, a3, a4, ha, Wr, acc);
        agg_edge(b0, b1, b2, b3, b4, hb, Wr, acc);
    }
    if (e < e1) {
        const float4* ra = (const float4*)(edgerec + (size_t)e * 20);
        float4 a0 = ra[0], a1 = ra[1], a2 = ra[2], a3 = ra[3], a4 = ra[4];
        int sa = __float_as_int(a4.y);
        float ha = h[(size_t)sa * 64 + lane];
        agg_edge(a0, a1, a2, a3, a4, ha, Wr, acc);
    }
    const float inv_avg = 1.0f / 16.0f;
#pragma unroll
    for (int m = 0; m < 9; ++m) A[(size_t)n * 576 + m * 64 + lane] = acc[m] * inv_avg;
}

// mix (X via LDS broadcast, W in LDS) + fused prod; only the m=0 row of B is
// live downstream -> store just Bm0[n][k]. 8 nodes/wave, manual prefetch.
__global__ void __launch_bounds__(256) k_mixprod(
    const float* __restrict__ A,
    float* __restrict__ Bm0,
    const float* __restrict__ Wm_i,    // 3*64*64
    const float* __restrict__ Wp_i) {  // [3][3][64]
    __shared__ float Wlds[3 * 4096];
    __shared__ float xtile[4][9 * 64];
    {
        float4* Wl4 = (float4*)Wlds;
        const float4* W4 = (const float4*)Wm_i;
#pragma unroll
        for (int i = 0; i < 12; ++i)
            Wl4[threadIdx.x + 256 * i] = W4[threadIdx.x + 256 * i];
    }
    __syncthreads();
    int lane = threadIdx.x & 63;
    int wid = threadIdx.x >> 6;
    float* xt = xtile[wid];
    float w10 = Wp_i[0 * 64 + lane], w11 = Wp_i[1 * 64 + lane], w12 = Wp_i[2 * 64 + lane];
    float w20 = Wp_i[3 * 64 + lane], w21 = Wp_i[4 * 64 + lane], w22 = Wp_i[5 * 64 + lane];
    float w30 = Wp_i[6 * 64 + lane], w31 = Wp_i[7 * 64 + lane], w32 = Wp_i[8 * 64 + lane];

    int n = blockIdx.x * 32 + wid * 8;
    float x[9];
#pragma unroll
    for (int m = 0; m < 9; ++m) x[m] = A[(size_t)n * 576 + m * 64 + lane];
    for (int it = 0; it < 8; ++it) {
#pragma unroll
        for (int m = 0; m < 9; ++m) xt[m * 64 + lane] = x[m];
        if (it < 7) {
            const float* An = A + (size_t)(n + 1) * 576;
#pragma unroll
            for (int m = 0; m < 9; ++m) x[m] = An[m * 64 + lane];  // prefetch
        }
        float acc[9];
#pragma unroll
        for (int m = 0; m < 9; ++m) acc[m] = 0.f;
#pragma unroll 2
        for (int c4 = 0; c4 < 16; ++c4) {
            float4 xb[9];
#pragma unroll
            for (int m = 0; m < 9; ++m)
                xb[m] = *(const float4*)&xt[m * 64 + c4 * 4];
#pragma unroll
            for (int j = 0; j < 4; ++j) {
                int k = c4 * 4 + j;
                float wv0 = Wlds[k * 64 + lane];
                float wv1 = Wlds[4096 + k * 64 + lane];
                float wv2 = Wlds[8192 + k * 64 + lane];
                acc[0] += f4c(xb[0], j) * wv0;
                acc[1] += f4c(xb[1], j) * wv1;
                acc[2] += f4c(xb[2], j) * wv1;
                acc[3] += f4c(xb[3], j) * wv1;
                acc[4] += f4c(xb[4], j) * wv2;
                acc[5] += f4c(xb[5], j) * wv2;
                acc[6] += f4c(xb[6], j) * wv2;
                acc[7] += f4c(xb[7], j) * wv2;
                acc[8] += f4c(xb[8], j) * wv2;
            }
        }
        float A0 = acc[0];
        float inv = 0.f;
#pragma unroll
        for (int m = 0; m < 9; ++m) inv += acc[m] * acc[m];
        Bm0[(size_t)n * 64 + lane] = acc[0] * (w10 + w20 * A0 + w30 * inv);
        ++n;
    }
}

// l=0 self-connection + energy epilogue over species-sorted nodes.
#define RPB 32
template <int ITER>
__global__ void __launch_bounds__(256) k_sc(
    const float* __restrict__ h_in,
    const float* __restrict__ Bm0,
    float* __restrict__ h_out,
    const int* __restrict__ ord,
    const int* __restrict__ sp_start,
    const float* __restrict__ Wsc_i,     // + sp*3*4096 selects [sp][l=0]
    const float* __restrict__ W_ro0,
    const float* __restrict__ W_m1,
    const float* __restrict__ b_m1,
    const float* __restrict__ W_m2,
    float* __restrict__ out) {
    const int BPS = NN / RPB;
    int sp = blockIdx.x / BPS;
    int c  = blockIdx.x - sp * BPS;
    int base = sp_start[sp];
    int cnt  = sp_start[sp + 1] - base;
    int r0 = c * RPB;
    __shared__ float Wlds[4096];
    __shared__ float xtile[4][8 * 64];
    if (r0 < cnt) {
        const float4* W4 = (const float4*)(Wsc_i + (size_t)sp * 3 * 4096);
        float4* Wl4 = (float4*)Wlds;
#pragma unroll
        for (int i = 0; i < 4; ++i)
            Wl4[threadIdx.x + 256 * i] = W4[threadIdx.x + 256 * i];
    }
    __syncthreads();
    if (r0 >= cnt) return;
    int lane = threadIdx.x & 63;
    int wid = threadIdx.x >> 6;
    float* xt = xtile[wid];
    int rend = min(r0 + RPB, cnt);
    int q0 = r0 + wid * 8;
    if (q0 >= rend) return;
    int nd[8];
#pragma unroll
    for (int t = 0; t < 8; ++t)
        nd[t] = ord[base + min(q0 + t, rend - 1)];
    float xv[8];
#pragma unroll
    for (int t = 0; t < 8; ++t) xv[t] = h_in[(size_t)nd[t] * 64 + lane];
#pragma unroll
    for (int t = 0; t < 8; ++t) xt[t * 64 + lane] = xv[t];
    float acc[8];
#pragma unroll
    for (int t = 0; t < 8; ++t) acc[t] = 0.f;
#pragma unroll 2
    for (int c4 = 0; c4 < 16; ++c4) {
        float wv[4];
#pragma unroll
        for (int j = 0; j < 4; ++j) wv[j] = Wlds[(c4 * 4 + j) * 64 + lane];
#pragma unroll
        for (int t = 0; t < 8; ++t) {
            float4 xb = *(const float4*)&xt[t * 64 + c4 * 4];
#pragma unroll
            for (int j = 0; j < 4; ++j) acc[t] += f4c(xb, j) * wv[j];
        }
    }
    float wro = W_ro0[lane];
#pragma unroll
    for (int t = 0; t < 8; ++t) {
        if (q0 + t >= rend) break;
        int node = nd[t];
        float outv = acc[t] + Bm0[(size_t)node * 64 + lane];
        if (ITER == 0) {
            h_out[(size_t)node * 64 + lane] = outv;
            float e = wave_reduce(outv * wro);
            if (lane == 0) out[2 * node + 0] = e;
        } else {
            int hh = lane & 15;
            float tacc = b_m1[hh];
#pragma unroll
            for (int k = 0; k < 64; ++k)
                tacc += __shfl(outv, k, 64) * W_m1[k * MLPH + hh];
            float sig = 1.0f / (1.0f + expf(-tacc));
            float contrib = (lane < MLPH) ? tacc * sig * W_m2[lane] : 0.f;
            float e = wave_reduce(contrib);
            if (lane == 0) out[2 * node + 1] = e;
        }
    }
}

extern "C" void kernel_launch(void* const* d_in, const int* in_sizes, int n_in,
                              void* d_out, int out_size, void* d_ws, size_t ws_size,
                              hipStream_t stream) {
    const float* positions = (const float*)d_in[0];
    const float* shifts    = (const float*)d_in[1];
    const int*   species   = (const int*)d_in[2];
    const int*   senders   = (const int*)d_in[3];
    const int*   receivers = (const int*)d_in[4];
    const float* W_embed   = (const float*)d_in[5];
    const float* W_rad     = (const float*)d_in[6];
    const float* W_mix     = (const float*)d_in[7];
    const float* W_prod    = (const float*)d_in[8];
    const float* W_sc      = (const float*)d_in[9];
    const float* W_ro0     = (const float*)d_in[10];
    const float* W_m1      = (const float*)d_in[11];
    const float* b_m1      = (const float*)d_in[12];
    const float* W_m2      = (const float*)d_in[13];
    float* out = (float*)d_out;

    char* p = (char*)d_ws;
    float* A       = (float*)p; p += (size_t)NN * 576 * 4;   // 37.75 MB
    float* edgerec = (float*)p; p += (size_t)NE * 20 * 4;    // 20.97 MB
    float* Bm0     = (float*)p; p += (size_t)NN * KC * 4;    //  4.19 MB
    float* h0      = (float*)p; p += (size_t)NN * KC * 4;    //  4.19 MB
    float* h1      = (float*)p; p += (size_t)NN * KC * 4;    //  4.19 MB
    int* ord       = (int*)p; p += (size_t)NN * 4;
    int* count     = (int*)p; p += (size_t)NN * 4;           // memset start
    int* cursor    = (int*)p; p += (size_t)NN * 4;
    int* sp_cnt    = (int*)p; p += 16 * 4;
    int* sp_cursor = (int*)p; p += 16 * 4;                   // memset end
    int* row_start = (int*)p; p += (size_t)(NN + 1) * 4;
    int* sp_start  = (int*)p; p += 16 * 4;

    hipMemsetAsync(count, 0, ((size_t)2 * NN + 32) * 4, stream);

    k_init_h0<<<NN * 16 / 256, 256, 0, stream>>>(W_embed, species, (float4*)h0);
    k_hist<<<NE / 256, 256, 0, stream>>>(receivers, count);
    k_hist_sp<<<NN / 256, 256, 0, stream>>>(species, sp_cnt);
    k_scan<<<1, 1024, 0, stream>>>(count, row_start, sp_cnt, sp_start);
    k_geom<<<NE / 256, 256, 0, stream>>>(positions, shifts, senders, receivers,
                                         row_start, cursor, edgerec);
    k_scatter_sp<<<NN / 256, 256, 0, stream>>>(species, sp_start, sp_cursor, ord);

    // ---- iteration 0 ----
    k_aggregate<<<NN / 4, 256, 0, stream>>>(h0, edgerec, row_start, W_rad + 0, A);
    k_mixprod<<<NN / 32, 256, 0, stream>>>(A, Bm0, W_mix + 0, W_prod + 0);
    k_sc<0><<<NSPEC * (NN / RPB), 256, 0, stream>>>(h0, Bm0, h1, ord, sp_start,
        W_sc + 0, W_ro0, W_m1, b_m1, W_m2, out);

    // ---- iteration 1 ----
    k_aggregate<<<NN / 4, 256, 0, stream>>>(h1, edgerec, row_start,
                                            W_rad + 3 * 8 * 64, A);
    k_mixprod<<<NN / 32, 256, 0, stream>>>(A, Bm0, W_mix + 3 * 4096,
                                           W_prod + 3 * 3 * 64);
    k_sc<1><<<NSPEC * (NN / RPB), 256, 0, stream>>>(h1, Bm0, h0 /*unused*/, ord,
        sp_start, W_sc + (size_t)NSPEC * 3 * 4096, W_ro0, W_m1, b_m1, W_m2, out);
}

// Round 5
// 439.126 us; speedup vs baseline: 2.1515x; 1.0877x over previous
//
#include <hip/hip_runtime.h>

#define NN 16384      // nodes
#define NE 262144     // edges
#define NSPEC 10
#define KC 64
#define MLPH 16

__device__ __forceinline__ float wave_reduce(float v) {
#pragma unroll
    for (int off = 32; off > 0; off >>= 1) v += __shfl_down(v, off, 64);
    return v;
}

__device__ __forceinline__ float f4c(const float4& v, int j) {
    const float* p = &v.x;   // j compile-time after unroll
    return p[j];
}

// merged prologue: receiver histogram + species histogram + h0 init
__global__ void k_pre(const float* __restrict__ W_embed,
                      const int* __restrict__ species,
                      const int* __restrict__ receivers,
                      int* __restrict__ count,
                      int* __restrict__ sp_cnt,
                      float4* __restrict__ h04) {
    int tid = blockIdx.x * 256 + threadIdx.x;   // grid NE/256
    atomicAdd(&count[receivers[tid]], 1);
    if (tid < NN) atomicAdd(&sp_cnt[species[tid]], 1);
    if (tid < NN * 16) {
        int n = tid >> 4, q = tid & 15;
        h04[tid] = reinterpret_cast<const float4*>(W_embed + species[n] * KC)[q];
    }
}

__global__ void k_scan(const int* __restrict__ count, int* __restrict__ row_start,
                       const int* __restrict__ sp_cnt, int* __restrict__ sp_start) {
    __shared__ int lds[1024];
    int t = threadIdx.x;
    int base = t * 16;
    int local[16];
    int s = 0;
#pragma unroll
    for (int b = 0; b < 16; ++b) { local[b] = count[base + b]; s += local[b]; }
    lds[t] = s;
    __syncthreads();
    for (int off = 1; off < 1024; off <<= 1) {
        int v = (t >= off) ? lds[t - off] : 0;
        __syncthreads();
        lds[t] += v;
        __syncthreads();
    }
    int run = lds[t] - s;
#pragma unroll
    for (int b = 0; b < 16; ++b) { row_start[base + b] = run; run += local[b]; }
    if (t == 1023) row_start[NN] = run;
    if (t == 0) {
        int r2 = 0;
        for (int sp = 0; sp < NSPEC; ++sp) { sp_start[sp] = r2; r2 += sp_cnt[sp]; }
        sp_start[NSPEC] = r2;
    }
}

// edge permutation (receiver-sorted) + species-sorted node order
__global__ void k_scatter(const int* __restrict__ receivers,
                          const int* __restrict__ row_start,
                          int* __restrict__ cursor,
                          int* __restrict__ eidx,
                          const int* __restrict__ species,
                          const int* __restrict__ sp_start,
                          int* __restrict__ sp_cursor,
                          int* __restrict__ ord) {
    int tid = blockIdx.x * 256 + threadIdx.x;   // grid NE/256
    int r = receivers[tid];
    int p = row_start[r] + atomicAdd(&cursor[r], 1);
    eidx[p] = tid;
    if (tid < NN) {
        int sp = species[tid];
        ord[sp_start[sp] + atomicAdd(&sp_cursor[sp], 1)] = tid;
    }
}

// geometry in sorted order: gather edge inputs, write dense 80B records
// rec = [Y0..Y8, rad0..rad7, s_bits, pad, pad]
__global__ void k_geom(const float* __restrict__ pos,
                       const float* __restrict__ shifts,
                       const int* __restrict__ senders,
                       const int* __restrict__ receivers,
                       const int* __restrict__ eidx,
                       float* __restrict__ edgerec) {
    int p = blockIdx.x * 256 + threadIdx.x;
    int e = eidx[p];
    int s = senders[e], r = receivers[e];
    float dx = pos[r * 3 + 0] - pos[s * 3 + 0] + shifts[e * 3 + 0];
    float dy = pos[r * 3 + 1] - pos[s * 3 + 1] + shifts[e * 3 + 1];
    float dz = pos[r * 3 + 2] - pos[s * 3 + 2] + shifts[e * 3 + 2];
    float rn = sqrtf(dx * dx + dy * dy + dz * dz);
    float den = (rn > 1e-9f) ? rn : 1.0f;
    float x = dx / den, y = dy / den, z = dz / den;
    const float s3  = 1.7320508075688772f;
    const float s15 = 3.8729833462074170f;
    const float s5h = 1.1180339887498949f;
    const float s15h = 1.9364916731037085f;
    float rec[20];
    rec[0] = 1.0f;
    rec[1] = s3 * x;
    rec[2] = s3 * y;
    rec[3] = s3 * z;
    rec[4] = s15 * x * y;
    rec[5] = s15 * y * z;
    rec[6] = s5h * (3.0f * z * z - 1.0f);
    rec[7] = s15 * x * z;
    rec[8] = s15h * (x * x - y * y);
    float u = rn * 0.2f;
    float env = 0.0f;
    if (u < 1.0f) {
        float u2 = u * u;
        float u5 = u2 * u2 * u;
        env = 1.0f - 21.0f * u5 + 35.0f * u5 * u - 15.0f * u5 * u2;
    }
    float pre = 0.63245553203367587f * env / den;
#pragma unroll
    for (int nb = 1; nb <= 8; ++nb)
        rec[8 + nb] = pre * sinf((float)nb * 3.14159265358979323846f * u);
    rec[17] = __int_as_float(s);
    rec[18] = 0.f; rec[19] = 0.f;
    float4* o = (float4*)(edgerec + (size_t)p * 20);
#pragma unroll
    for (int i = 0; i < 5; ++i)
        o[i] = make_float4(rec[4 * i], rec[4 * i + 1], rec[4 * i + 2], rec[4 * i + 3]);
}

__device__ __forceinline__ void agg_edge(const float* __restrict__ rec, float hv,
                                         const float (&Wr)[3][8], float (&acc)[9]) {
    float R0 = 0.f, R1 = 0.f, R2 = 0.f;
#pragma unroll
    for (int b = 0; b < 8; ++b) {
        float rb = rec[9 + b];
        R0 += rb * Wr[0][b];
        R1 += rb * Wr[1][b];
        R2 += rb * Wr[2][b];
    }
    float t0 = hv * R0, t1 = hv * R1, t2 = hv * R2;
    acc[0] += t0 * rec[0];
    acc[1] += t1 * rec[1];
    acc[2] += t1 * rec[2];
    acc[3] += t1 * rec[3];
    acc[4] += t2 * rec[4];
    acc[5] += t2 * rec[5];
    acc[6] += t2 * rec[6];
    acc[7] += t2 * rec[7];
    acc[8] += t2 * rec[8];
}

// one WAVE per block; node indices derived from blockIdx only -> edgerec
// addresses are block-uniform -> compiler emits scalar (SMEM) loads, leaving
// VMEM for the h-gathers and A-stores only.
#define AGG_NPB 4
__global__ void __launch_bounds__(64) k_aggregate(
    const float* __restrict__ h,
    const float* __restrict__ edgerec,
    const int* __restrict__ row_start,
    const float* __restrict__ Wr_i,    // [l][b][k]
    float* __restrict__ A) {
    int lane = threadIdx.x;
    float Wr[3][8];
#pragma unroll
    for (int l = 0; l < 3; ++l)
#pragma unroll
        for (int b = 0; b < 8; ++b) Wr[l][b] = Wr_i[(l * 8 + b) * 64 + lane];
    int n0 = blockIdx.x * AGG_NPB;
    for (int it = 0; it < AGG_NPB; ++it) {
        int n = n0 + it;
        float acc[9];
#pragma unroll
        for (int m = 0; m < 9; ++m) acc[m] = 0.f;
        int e0 = row_start[n], e1 = row_start[n + 1];
        int e = e0;
        for (; e + 2 <= e1; e += 2) {
            const float* ra = edgerec + (size_t)e * 20;
            const float* rb = ra + 20;
            int sa = __float_as_int(ra[17]);
            int sb = __float_as_int(rb[17]);
            float ha = h[(size_t)sa * 64 + lane];
            float hb = h[(size_t)sb * 64 + lane];
            agg_edge(ra, ha, Wr, acc);
            agg_edge(rb, hb, Wr, acc);
        }
        if (e < e1) {
            const float* ra = edgerec + (size_t)e * 20;
            int sa = __float_as_int(ra[17]);
            float ha = h[(size_t)sa * 64 + lane];
            agg_edge(ra, ha, Wr, acc);
        }
        const float inv_avg = 1.0f / 16.0f;
        float* An = A + (size_t)n * 576;
#pragma unroll
        for (int m = 0; m < 9; ++m) An[m * 64 + lane] = acc[m] * inv_avg;
    }
}

// mix (X via LDS broadcast, W in LDS) + fused prod; only m=0 stored.
__global__ void __launch_bounds__(256) k_mixprod(
    const float* __restrict__ A,
    float* __restrict__ Bm0,
    const float* __restrict__ Wm_i,    // 3*64*64
    const float* __restrict__ Wp_i) {  // [3][3][64]
    __shared__ float Wlds[3 * 4096];
    __shared__ float xtile[4][9 * 64];
    {
        float4* Wl4 = (float4*)Wlds;
        const float4* W4 = (const float4*)Wm_i;
#pragma unroll
        for (int i = 0; i < 12; ++i)
            Wl4[threadIdx.x + 256 * i] = W4[threadIdx.x + 256 * i];
    }
    __syncthreads();
    int lane = threadIdx.x & 63;
    int wid = threadIdx.x >> 6;
    float* xt = xtile[wid];
    float w10 = Wp_i[0 * 64 + lane];           // w1[l=0]
    float w20 = Wp_i[3 * 64 + lane];           // w2[l=0]
    float w30 = Wp_i[6 * 64 + lane];           // w3[l=0]

    int n = blockIdx.x * 32 + wid * 8;
    float x[9];
#pragma unroll
    for (int m = 0; m < 9; ++m) x[m] = A[(size_t)n * 576 + m * 64 + lane];
    for (int it = 0; it < 8; ++it) {
#pragma unroll
        for (int m = 0; m < 9; ++m) xt[m * 64 + lane] = x[m];
        if (it < 7) {
            const float* An = A + (size_t)(n + 1) * 576;
#pragma unroll
            for (int m = 0; m < 9; ++m) x[m] = An[m * 64 + lane];  // prefetch
        }
        float acc[9];
#pragma unroll
        for (int m = 0; m < 9; ++m) acc[m] = 0.f;
#pragma unroll 2
        for (int c4 = 0; c4 < 16; ++c4) {
            float4 xb[9];
#pragma unroll
            for (int m = 0; m < 9; ++m)
                xb[m] = *(const float4*)&xt[m * 64 + c4 * 4];
#pragma unroll
            for (int j = 0; j < 4; ++j) {
                int k = c4 * 4 + j;
                float wv0 = Wlds[k * 64 + lane];
                float wv1 = Wlds[4096 + k * 64 + lane];
                float wv2 = Wlds[8192 + k * 64 + lane];
                acc[0] += f4c(xb[0], j) * wv0;
                acc[1] += f4c(xb[1], j) * wv1;
                acc[2] += f4c(xb[2], j) * wv1;
                acc[3] += f4c(xb[3], j) * wv1;
                acc[4] += f4c(xb[4], j) * wv2;
                acc[5] += f4c(xb[5], j) * wv2;
                acc[6] += f4c(xb[6], j) * wv2;
                acc[7] += f4c(xb[7], j) * wv2;
                acc[8] += f4c(xb[8], j) * wv2;
            }
        }
        float A0 = acc[0];
        float inv = 0.f;
#pragma unroll
        for (int m = 0; m < 9; ++m) inv += acc[m] * acc[m];
        Bm0[(size_t)n * 64 + lane] = acc[0] * (w10 + w20 * A0 + w30 * inv);
        ++n;
    }
}

// l=0 self-connection + energy epilogue over species-sorted nodes.
#define RPB 32
template <int ITER>
__global__ void __launch_bounds__(256) k_sc(
    const float* __restrict__ h_in,
    const float* __restrict__ Bm0,
    float* __restrict__ h_out,
    const int* __restrict__ ord,
    const int* __restrict__ sp_start,
    const float* __restrict__ Wsc_i,     // + sp*3*4096 selects [sp][l=0]
    const float* __restrict__ W_ro0,
    const float* __restrict__ W_m1,
    const float* __restrict__ b_m1,
    const float* __restrict__ W_m2,
    float* __restrict__ out) {
    const int BPS = NN / RPB;
    int sp = blockIdx.x / BPS;
    int c  = blockIdx.x - sp * BPS;
    int base = sp_start[sp];
    int cnt  = sp_start[sp + 1] - base;
    int r0 = c * RPB;
    __shared__ float Wlds[4096];
    __shared__ float xtile[4][8 * 64];
    if (r0 < cnt) {
        const float4* W4 = (const float4*)(Wsc_i + (size_t)sp * 3 * 4096);
        float4* Wl4 = (float4*)Wlds;
#pragma unroll
        for (int i = 0; i < 4; ++i)
            Wl4[threadIdx.x + 256 * i] = W4[threadIdx.x + 256 * i];
    }
    __syncthreads();
    if (r0 >= cnt) return;
    int lane = threadIdx.x & 63;
    int wid = threadIdx.x >> 6;
    float* xt = xtile[wid];
    int rend = min(r0 + RPB, cnt);
    int q0 = r0 + wid * 8;
    if (q0 >= rend) return;
    int nd[8];
#pragma unroll
    for (int t = 0; t < 8; ++t)
        nd[t] = ord[base + min(q0 + t, rend - 1)];
    float xv[8];
#pragma unroll
    for (int t = 0; t < 8; ++t) xv[t] = h_in[(size_t)nd[t] * 64 + lane];
#pragma unroll
    for (int t = 0; t < 8; ++t) xt[t * 64 + lane] = xv[t];
    float acc[8];
#pragma unroll
    for (int t = 0; t < 8; ++t) acc[t] = 0.f;
#pragma unroll 2
    for (int c4 = 0; c4 < 16; ++c4) {
        float wv[4];
#pragma unroll
        for (int j = 0; j < 4; ++j) wv[j] = Wlds[(c4 * 4 + j) * 64 + lane];
#pragma unroll
        for (int t = 0; t < 8; ++t) {
            float4 xb = *(const float4*)&xt[t * 64 + c4 * 4];
#pragma unroll
            for (int j = 0; j < 4; ++j) acc[t] += f4c(xb, j) * wv[j];
        }
    }
    float wro = W_ro0[lane];
#pragma unroll
    for (int t = 0; t < 8; ++t) {
        if (q0 + t >= rend) break;
        int node = nd[t];
        float outv = acc[t] + Bm0[(size_t)node * 64 + lane];
        if (ITER == 0) {
            h_out[(size_t)node * 64 + lane] = outv;
            float e = wave_reduce(outv * wro);
            if (lane == 0) out[2 * node + 0] = e;
        } else {
            int hh = lane & 15;
            float tacc = b_m1[hh];
#pragma unroll
            for (int k = 0; k < 64; ++k)
                tacc += __shfl(outv, k, 64) * W_m1[k * MLPH + hh];
            float sig = 1.0f / (1.0f + expf(-tacc));
            float contrib = (lane < MLPH) ? tacc * sig * W_m2[lane] : 0.f;
            float e = wave_reduce(contrib);
            if (lane == 0) out[2 * node + 1] = e;
        }
    }
}

extern "C" void kernel_launch(void* const* d_in, const int* in_sizes, int n_in,
                              void* d_out, int out_size, void* d_ws, size_t ws_size,
                              hipStream_t stream) {
    const float* positions = (const float*)d_in[0];
    const float* shifts    = (const float*)d_in[1];
    const int*   species   = (const int*)d_in[2];
    const int*   senders   = (const int*)d_in[3];
    const int*   receivers = (const int*)d_in[4];
    const float* W_embed   = (const float*)d_in[5];
    const float* W_rad     = (const float*)d_in[6];
    const float* W_mix     = (const float*)d_in[7];
    const float* W_prod    = (const float*)d_in[8];
    const float* W_sc      = (const float*)d_in[9];
    const float* W_ro0     = (const float*)d_in[10];
    const float* W_m1      = (const float*)d_in[11];
    const float* b_m1      = (const float*)d_in[12];
    const float* W_m2      = (const float*)d_in[13];
    float* out = (float*)d_out;

    char* p = (char*)d_ws;
    float* A       = (float*)p; p += (size_t)NN * 576 * 4;   // 37.75 MB
    float* edgerec = (float*)p; p += (size_t)NE * 20 * 4;    // 20.97 MB
    float* Bm0     = (float*)p; p += (size_t)NN * KC * 4;    //  4.19 MB
    float* h0      = (float*)p; p += (size_t)NN * KC * 4;    //  4.19 MB
    float* h1      = (float*)p; p += (size_t)NN * KC * 4;    //  4.19 MB
    int* eidx      = (int*)p; p += (size_t)NE * 4;           //  1.05 MB
    int* ord       = (int*)p; p += (size_t)NN * 4;
    int* count     = (int*)p; p += (size_t)NN * 4;           // memset start
    int* cursor    = (int*)p; p += (size_t)NN * 4;
    int* sp_cnt    = (int*)p; p += 16 * 4;
    int* sp_cursor = (int*)p; p += 16 * 4;                   // memset end
    int* row_start = (int*)p; p += (size_t)(NN + 1) * 4;
    int* sp_start  = (int*)p; p += 16 * 4;

    hipMemsetAsync(count, 0, ((size_t)2 * NN + 32) * 4, stream);

    k_pre<<<NE / 256, 256, 0, stream>>>(W_embed, species, receivers,
                                        count, sp_cnt, (float4*)h0);
    k_scan<<<1, 1024, 0, stream>>>(count, row_start, sp_cnt, sp_start);
    k_scatter<<<NE / 256, 256, 0, stream>>>(receivers, row_start, cursor, eidx,
                                            species, sp_start, sp_cursor, ord);
    k_geom<<<NE / 256, 256, 0, stream>>>(positions, shifts, senders, receivers,
                                         eidx, edgerec);

    // ---- iteration 0 ----
    k_aggregate<<<NN / AGG_NPB, 64, 0, stream>>>(h0, edgerec, row_start,
                                                 W_rad + 0, A);
    k_mixprod<<<NN / 32, 256, 0, stream>>>(A, Bm0, W_mix + 0, W_prod + 0);
    k_sc<0><<<NSPEC * (NN / RPB), 256, 0, stream>>>(h0, Bm0, h1, ord, sp_start,
        W_sc + 0, W_ro0, W_m1, b_m1, W_m2, out);

    // ---- iteration 1 ----
    k_aggregate<<<NN / AGG_NPB, 64, 0, stream>>>(h1, edgerec, row_start,
                                                 W_rad + 3 * 8 * 64, A);
    k_mixprod<<<NN / 32, 256, 0, stream>>>(A, Bm0, W_mix + 3 * 4096,
                                           W_prod + 3 * 3 * 64);
    k_sc<1><<<NSPEC * (NN / RPB), 256, 0, stream>>>(h1, Bm0, h0 /*unused*/, ord,
        sp_start, W_sc + (size_t)NSPEC * 3 * 4096, W_ro0, W_m1, b_m1, W_m2, out);
}

// Round 6
// 371.427 us; speedup vs baseline: 2.5436x; 1.1823x over previous
//
#include <hip/hip_runtime.h>

#define NN 16384      // nodes
#define NE 262144     // edges
#define NSPEC 10
#define KC 64
#define MLPH 16

__device__ __forceinline__ float wave_reduce(float v) {
#pragma unroll
    for (int off = 32; off > 0; off >>= 1) v += __shfl_down(v, off, 64);
    return v;
}

__device__ __forceinline__ float f4c(const float4& v, int j) {
    const float* p = &v.x;   // j compile-time after unroll
    return p[j];
}

// merged prologue: receiver slot assignment (fetch-add, dense slot store),
// species slot assignment, h0 init.  grid = NE/256; NN*16 == NE.
__global__ void k_pre(const float* __restrict__ W_embed,
                      const int* __restrict__ species,
                      const int* __restrict__ receivers,
                      int* __restrict__ count,
                      int* __restrict__ sp_cnt,
                      int* __restrict__ eslot,
                      int* __restrict__ nslot,
                      float4* __restrict__ h04) {
    int tid = blockIdx.x * 256 + threadIdx.x;
    eslot[tid] = atomicAdd(&count[receivers[tid]], 1);   // dense coalesced store
    if (tid < NN) nslot[tid] = atomicAdd(&sp_cnt[species[tid]], 1);
    int n = tid >> 4, q = tid & 15;
    h04[tid] = reinterpret_cast<const float4*>(W_embed + species[n] * KC)[q];
}

__global__ void k_scan(const int* __restrict__ count, int* __restrict__ row_start,
                       const int* __restrict__ sp_cnt, int* __restrict__ sp_start) {
    __shared__ int lds[1024];
    int t = threadIdx.x;
    int base = t * 16;
    int local[16];
    int s = 0;
#pragma unroll
    for (int b = 0; b < 16; ++b) { local[b] = count[base + b]; s += local[b]; }
    lds[t] = s;
    __syncthreads();
    for (int off = 1; off < 1024; off <<= 1) {
        int v = (t >= off) ? lds[t - off] : 0;
        __syncthreads();
        lds[t] += v;
        __syncthreads();
    }
    int run = lds[t] - s;
#pragma unroll
    for (int b = 0; b < 16; ++b) { row_start[base + b] = run; run += local[b]; }
    if (t == 1023) row_start[NN] = run;
    if (t == 0) {
        int r2 = 0;
        for (int sp = 0; sp < NSPEC; ++sp) { sp_start[sp] = r2; r2 += sp_cnt[sp]; }
        sp_start[NSPEC] = r2;
    }
}

// geometry: compute per-edge record, write to receiver-sorted slot
// p = row_start[r] + eslot[e] (no atomics).  Also scatters the species-sorted
// node order (ord) for the first NN threads.
// rec = [Y0..Y8, rad0..rad7, s_bits, pad, pad]
__global__ void k_geom(const float* __restrict__ pos,
                       const float* __restrict__ shifts,
                       const int* __restrict__ senders,
                       const int* __restrict__ receivers,
                       const int* __restrict__ row_start,
                       const int* __restrict__ eslot,
                       const int* __restrict__ species,
                       const int* __restrict__ sp_start,
                       const int* __restrict__ nslot,
                       int* __restrict__ ord,
                       float* __restrict__ edgerec) {
    int e = blockIdx.x * 256 + threadIdx.x;
    if (e < NN) {
        int sp = species[e];
        ord[sp_start[sp] + nslot[e]] = e;
    }
    int s = senders[e], r = receivers[e];
    float dx = pos[r * 3 + 0] - pos[s * 3 + 0] + shifts[e * 3 + 0];
    float dy = pos[r * 3 + 1] - pos[s * 3 + 1] + shifts[e * 3 + 1];
    float dz = pos[r * 3 + 2] - pos[s * 3 + 2] + shifts[e * 3 + 2];
    float rn = sqrtf(dx * dx + dy * dy + dz * dz);
    float den = (rn > 1e-9f) ? rn : 1.0f;
    float x = dx / den, y = dy / den, z = dz / den;
    const float s3  = 1.7320508075688772f;
    const float s15 = 3.8729833462074170f;
    const float s5h = 1.1180339887498949f;
    const float s15h = 1.9364916731037085f;
    float rec[20];
    rec[0] = 1.0f;
    rec[1] = s3 * x;
    rec[2] = s3 * y;
    rec[3] = s3 * z;
    rec[4] = s15 * x * y;
    rec[5] = s15 * y * z;
    rec[6] = s5h * (3.0f * z * z - 1.0f);
    rec[7] = s15 * x * z;
    rec[8] = s15h * (x * x - y * y);
    float u = rn * 0.2f;
    float env = 0.0f;
    if (u < 1.0f) {
        float u2 = u * u;
        float u5 = u2 * u2 * u;
        env = 1.0f - 21.0f * u5 + 35.0f * u5 * u - 15.0f * u5 * u2;
    }
    float pre = 0.63245553203367587f * env / den;
#pragma unroll
    for (int nb = 1; nb <= 8; ++nb)
        rec[8 + nb] = pre * sinf((float)nb * 3.14159265358979323846f * u);
    rec[17] = __int_as_float(s);
    rec[18] = 0.f; rec[19] = 0.f;
    int p = row_start[r] + eslot[e];
    float4* o = (float4*)(edgerec + (size_t)p * 20);
#pragma unroll
    for (int i = 0; i < 5; ++i)
        o[i] = make_float4(rec[4 * i], rec[4 * i + 1], rec[4 * i + 2], rec[4 * i + 3]);
}

__device__ __forceinline__ void agg_edge(const float* __restrict__ rec, float hv,
                                         const float (&Wr)[3][8], float (&acc)[9]) {
    float R0 = 0.f, R1 = 0.f, R2 = 0.f;
#pragma unroll
    for (int b = 0; b < 8; ++b) {
        float rb = rec[9 + b];
        R0 += rb * Wr[0][b];
        R1 += rb * Wr[1][b];
        R2 += rb * Wr[2][b];
    }
    float t0 = hv * R0, t1 = hv * R1, t2 = hv * R2;
    acc[0] += t0 * rec[0];
    acc[1] += t1 * rec[1];
    acc[2] += t1 * rec[2];
    acc[3] += t1 * rec[3];
    acc[4] += t2 * rec[4];
    acc[5] += t2 * rec[5];
    acc[6] += t2 * rec[6];
    acc[7] += t2 * rec[7];
    acc[8] += t2 * rec[8];
}

// one WAVE per block; node indices derived from blockIdx only -> edgerec
// addresses are block-uniform -> scalar (SMEM) loads; VMEM carries only the
// h-gathers and A-stores.
#define AGG_NPB 4
__global__ void __launch_bounds__(64) k_aggregate(
    const float* __restrict__ h,
    const float* __restrict__ edgerec,
    const int* __restrict__ row_start,
    const float* __restrict__ Wr_i,    // [l][b][k]
    float* __restrict__ A) {
    int lane = threadIdx.x;
    float Wr[3][8];
#pragma unroll
    for (int l = 0; l < 3; ++l)
#pragma unroll
        for (int b = 0; b < 8; ++b) Wr[l][b] = Wr_i[(l * 8 + b) * 64 + lane];
    int n0 = blockIdx.x * AGG_NPB;
    for (int it = 0; it < AGG_NPB; ++it) {
        int n = n0 + it;
        float acc[9];
#pragma unroll
        for (int m = 0; m < 9; ++m) acc[m] = 0.f;
        int e0 = row_start[n], e1 = row_start[n + 1];
        int e = e0;
        for (; e + 2 <= e1; e += 2) {
            const float* ra = edgerec + (size_t)e * 20;
            const float* rb = ra + 20;
            int sa = __float_as_int(ra[17]);
            int sb = __float_as_int(rb[17]);
            float ha = h[(size_t)sa * 64 + lane];
            float hb = h[(size_t)sb * 64 + lane];
            agg_edge(ra, ha, Wr, acc);
            agg_edge(rb, hb, Wr, acc);
        }
        if (e < e1) {
            const float* ra = edgerec + (size_t)e * 20;
            int sa = __float_as_int(ra[17]);
            float ha = h[(size_t)sa * 64 + lane];
            agg_edge(ra, ha, Wr, acc);
        }
        const float inv_avg = 1.0f / 16.0f;
        float* An = A + (size_t)n * 576;
#pragma unroll
        for (int m = 0; m < 9; ++m) An[m * 64 + lane] = acc[m] * inv_avg;
    }
}

// mix (X via LDS broadcast, W in LDS) + fused prod; only m=0 stored.
__global__ void __launch_bounds__(256) k_mixprod(
    const float* __restrict__ A,
    float* __restrict__ Bm0,
    const float* __restrict__ Wm_i,    // 3*64*64
    const float* __restrict__ Wp_i) {  // [3][3][64]
    __shared__ float Wlds[3 * 4096];
    __shared__ float xtile[4][9 * 64];
    {
        float4* Wl4 = (float4*)Wlds;
        const float4* W4 = (const float4*)Wm_i;
#pragma unroll
        for (int i = 0; i < 12; ++i)
            Wl4[threadIdx.x + 256 * i] = W4[threadIdx.x + 256 * i];
    }
    __syncthreads();
    int lane = threadIdx.x & 63;
    int wid = threadIdx.x >> 6;
    float* xt = xtile[wid];
    float w10 = Wp_i[0 * 64 + lane];           // w1[l=0]
    float w20 = Wp_i[3 * 64 + lane];           // w2[l=0]
    float w30 = Wp_i[6 * 64 + lane];           // w3[l=0]

    int n = blockIdx.x * 32 + wid * 8;
    float x[9];
#pragma unroll
    for (int m = 0; m < 9; ++m) x[m] = A[(size_t)n * 576 + m * 64 + lane];
    for (int it = 0; it < 8; ++it) {
#pragma unroll
        for (int m = 0; m < 9; ++m) xt[m * 64 + lane] = x[m];
        if (it < 7) {
            const float* An = A + (size_t)(n + 1) * 576;
#pragma unroll
            for (int m = 0; m < 9; ++m) x[m] = An[m * 64 + lane];  // prefetch
        }
        float acc[9];
#pragma unroll
        for (int m = 0; m < 9; ++m) acc[m] = 0.f;
#pragma unroll 2
        for (int c4 = 0; c4 < 16; ++c4) {
            float4 xb[9];
#pragma unroll
            for (int m = 0; m < 9; ++m)
                xb[m] = *(const float4*)&xt[m * 64 + c4 * 4];
#pragma unroll
            for (int j = 0; j < 4; ++j) {
                int k = c4 * 4 + j;
                float wv0 = Wlds[k * 64 + lane];
                float wv1 = Wlds[4096 + k * 64 + lane];
                float wv2 = Wlds[8192 + k * 64 + lane];
                acc[0] += f4c(xb[0], j) * wv0;
                acc[1] += f4c(xb[1], j) * wv1;
                acc[2] += f4c(xb[2], j) * wv1;
                acc[3] += f4c(xb[3], j) * wv1;
                acc[4] += f4c(xb[4], j) * wv2;
                acc[5] += f4c(xb[5], j) * wv2;
                acc[6] += f4c(xb[6], j) * wv2;
                acc[7] += f4c(xb[7], j) * wv2;
                acc[8] += f4c(xb[8], j) * wv2;
            }
        }
        float A0 = acc[0];
        float inv = 0.f;
#pragma unroll
        for (int m = 0; m < 9; ++m) inv += acc[m] * acc[m];
        Bm0[(size_t)n * 64 + lane] = acc[0] * (w10 + w20 * A0 + w30 * inv);
        ++n;
    }
}

// l=0 self-connection + energy epilogue over species-sorted nodes.
#define RPB 32
template <int ITER>
__global__ void __launch_bounds__(256) k_sc(
    const float* __restrict__ h_in,
    const float* __restrict__ Bm0,
    float* __restrict__ h_out,
    const int* __restrict__ ord,
    const int* __restrict__ sp_start,
    const float* __restrict__ Wsc_i,     // + sp*3*4096 selects [sp][l=0]
    const float* __restrict__ W_ro0,
    const float* __restrict__ W_m1,
    const float* __restrict__ b_m1,
    const float* __restrict__ W_m2,
    float* __restrict__ out) {
    const int BPS = NN / RPB;
    int sp = blockIdx.x / BPS;
    int c  = blockIdx.x - sp * BPS;
    int base = sp_start[sp];
    int cnt  = sp_start[sp + 1] - base;
    int r0 = c * RPB;
    __shared__ float Wlds[4096];
    __shared__ float xtile[4][8 * 64];
    if (r0 < cnt) {
        const float4* W4 = (const float4*)(Wsc_i + (size_t)sp * 3 * 4096);
        float4* Wl4 = (float4*)Wlds;
#pragma unroll
        for (int i = 0; i < 4; ++i)
            Wl4[threadIdx.x + 256 * i] = W4[threadIdx.x + 256 * i];
    }
    __syncthreads();
    if (r0 >= cnt) return;
    int lane = threadIdx.x & 63;
    int wid = threadIdx.x >> 6;
    float* xt = xtile[wid];
    int rend = min(r0 + RPB, cnt);
    int q0 = r0 + wid * 8;
    if (q0 >= rend) return;
    int nd[8];
#pragma unroll
    for (int t = 0; t < 8; ++t)
        nd[t] = ord[base + min(q0 + t, rend - 1)];
    float xv[8];
#pragma unroll
    for (int t = 0; t < 8; ++t) xv[t] = h_in[(size_t)nd[t] * 64 + lane];
#pragma unroll
    for (int t = 0; t < 8; ++t) xt[t * 64 + lane] = xv[t];
    float acc[8];
#pragma unroll
    for (int t = 0; t < 8; ++t) acc[t] = 0.f;
#pragma unroll 2
    for (int c4 = 0; c4 < 16; ++c4) {
        float wv[4];
#pragma unroll
        for (int j = 0; j < 4; ++j) wv[j] = Wlds[(c4 * 4 + j) * 64 + lane];
#pragma unroll
        for (int t = 0; t < 8; ++t) {
            float4 xb = *(const float4*)&xt[t * 64 + c4 * 4];
#pragma unroll
            for (int j = 0; j < 4; ++j) acc[t] += f4c(xb, j) * wv[j];
        }
    }
    float wro = W_ro0[lane];
#pragma unroll
    for (int t = 0; t < 8; ++t) {
        if (q0 + t >= rend) break;
        int node = nd[t];
        float outv = acc[t] + Bm0[(size_t)node * 64 + lane];
        if (ITER == 0) {
            h_out[(size_t)node * 64 + lane] = outv;
            float e = wave_reduce(outv * wro);
            if (lane == 0) out[2 * node + 0] = e;
        } else {
            int hh = lane & 15;
            float tacc = b_m1[hh];
#pragma unroll
            for (int k = 0; k < 64; ++k)
                tacc += __shfl(outv, k, 64) * W_m1[k * MLPH + hh];
            float sig = 1.0f / (1.0f + expf(-tacc));
            float contrib = (lane < MLPH) ? tacc * sig * W_m2[lane] : 0.f;
            float e = wave_reduce(contrib);
            if (lane == 0) out[2 * node + 1] = e;
        }
    }
}

extern "C" void kernel_launch(void* const* d_in, const int* in_sizes, int n_in,
                              void* d_out, int out_size, void* d_ws, size_t ws_size,
                              hipStream_t stream) {
    const float* positions = (const float*)d_in[0];
    const float* shifts    = (const float*)d_in[1];
    const int*   species   = (const int*)d_in[2];
    const int*   senders   = (const int*)d_in[3];
    const int*   receivers = (const int*)d_in[4];
    const float* W_embed   = (const float*)d_in[5];
    const float* W_rad     = (const float*)d_in[6];
    const float* W_mix     = (const float*)d_in[7];
    const float* W_prod    = (const float*)d_in[8];
    const float* W_sc      = (const float*)d_in[9];
    const float* W_ro0     = (const float*)d_in[10];
    const float* W_m1      = (const float*)d_in[11];
    const float* b_m1      = (const float*)d_in[12];
    const float* W_m2      = (const float*)d_in[13];
    float* out = (float*)d_out;

    char* p = (char*)d_ws;
    float* A       = (float*)p; p += (size_t)NN * 576 * 4;   // 37.75 MB
    float* edgerec = (float*)p; p += (size_t)NE * 20 * 4;    // 20.97 MB
    float* Bm0     = (float*)p; p += (size_t)NN * KC * 4;    //  4.19 MB
    float* h0      = (float*)p; p += (size_t)NN * KC * 4;    //  4.19 MB
    float* h1      = (float*)p; p += (size_t)NN * KC * 4;    //  4.19 MB
    int* eslot     = (int*)p; p += (size_t)NE * 4;           //  1.05 MB
    int* nslot     = (int*)p; p += (size_t)NN * 4;
    int* ord       = (int*)p; p += (size_t)NN * 4;
    int* count     = (int*)p; p += (size_t)NN * 4;           // memset start
    int* sp_cnt    = (int*)p; p += 16 * 4;                   // memset end
    int* row_start = (int*)p; p += (size_t)(NN + 1) * 4;
    int* sp_start  = (int*)p; p += 16 * 4;

    hipMemsetAsync(count, 0, ((size_t)NN + 16) * 4, stream);

    k_pre<<<NE / 256, 256, 0, stream>>>(W_embed, species, receivers,
                                        count, sp_cnt, eslot, nslot, (float4*)h0);
    k_scan<<<1, 1024, 0, stream>>>(count, row_start, sp_cnt, sp_start);
    k_geom<<<NE / 256, 256, 0, stream>>>(positions, shifts, senders, receivers,
                                         row_start, eslot, species, sp_start,
                                         nslot, ord, edgerec);

    // ---- iteration 0 ----
    k_aggregate<<<NN / AGG_NPB, 64, 0, stream>>>(h0, edgerec, row_start,
                                                 W_rad + 0, A);
    k_mixprod<<<NN / 32, 256, 0, stream>>>(A, Bm0, W_mix + 0, W_prod + 0);
    k_sc<0><<<NSPEC * (NN / RPB), 256, 0, stream>>>(h0, Bm0, h1, ord, sp_start,
        W_sc + 0, W_ro0, W_m1, b_m1, W_m2, out);

    // ---- iteration 1 ----
    k_aggregate<<<NN / AGG_NPB, 64, 0, stream>>>(h1, edgerec, row_start,
                                                 W_rad + 3 * 8 * 64, A);
    k_mixprod<<<NN / 32, 256, 0, stream>>>(A, Bm0, W_mix + 3 * 4096,
                                           W_prod + 3 * 3 * 64);
    k_sc<1><<<NSPEC * (NN / RPB), 256, 0, stream>>>(h1, Bm0, h0 /*unused*/, ord,
        sp_start, W_sc + (size_t)NSPEC * 3 * 4096, W_ro0, W_m1, b_m1, W_m2, out);
}

// Round 7
// 360.552 us; speedup vs baseline: 2.6203x; 1.0302x over previous
//
#include <hip/hip_runtime.h>

#define NN 16384      // nodes
#define NE 262144     // edges
#define NSPEC 10
#define KC 64
#define MLPH 16
#define SEG 128       // edge segments
#define EPSG 2048     // edges per segment = NE/SEG

__device__ __forceinline__ float wave_reduce(float v) {
#pragma unroll
    for (int off = 32; off > 0; off >>= 1) v += __shfl_down(v, off, 64);
    return v;
}

__device__ __forceinline__ float f4c(const float4& v, int j) {
    const float* p = &v.x;   // j compile-time after unroll
    return p[j];
}

// 128 blocks x 1024 threads. Per-block PRIVATE full histogram in LDS (64 KB):
// eslot[e] = rank of edge within (segment, receiver) -- LDS fetch-add, no
// global atomics. Segment counts dumped as u16. Also inits h0.
__global__ void __launch_bounds__(1024) k_pre(
    const float* __restrict__ W_embed,
    const int* __restrict__ species,
    const int* __restrict__ receivers,
    int* __restrict__ eslot,
    unsigned short* __restrict__ cnt16,    // [SEG][NN]
    float4* __restrict__ h04) {
    __shared__ int cntL[NN];
    int t = threadIdx.x;
#pragma unroll
    for (int i = 0; i < 16; ++i) cntL[t + 1024 * i] = 0;
    __syncthreads();
    int ebase = blockIdx.x * EPSG;
#pragma unroll
    for (int j = 0; j < EPSG / 1024; ++j) {
        int e = ebase + j * 1024 + t;
        int r = receivers[e];
        eslot[e] = atomicAdd(&cntL[r], 1);   // LDS atomic (ds_add_rtn)
    }
    // h0 init: 131072 threads x 2 float4 = NN*16
    int gt = blockIdx.x * 1024 + t;
#pragma unroll
    for (int q = 0; q < 2; ++q) {
        int idx = gt * 2 + q;
        int n = idx >> 4, w = idx & 15;
        h04[idx] = reinterpret_cast<const float4*>(W_embed + species[n] * KC)[w];
    }
    __syncthreads();
    unsigned short* o = cnt16 + (size_t)blockIdx.x * NN;
#pragma unroll
    for (int i = 0; i < 16; ++i)
        o[t + 1024 * i] = (unsigned short)cntL[t + 1024 * i];
}

// per-receiver column scan across segments: seg_base[g][r] = prefix,
// count[r] = total.  grid NN/128 x 128.
__global__ void __launch_bounds__(128) k_colscan(
    const unsigned short* __restrict__ cnt16,
    int* __restrict__ seg_base,            // [SEG][NN]
    int* __restrict__ count) {
    int r = blockIdx.x * 128 + threadIdx.x;
    int run = 0;
#pragma unroll 4
    for (int g = 0; g < SEG; ++g) {
        int c = cnt16[(size_t)g * NN + r];
        seg_base[(size_t)g * NN + r] = run;
        run += c;
    }
    count[r] = run;
}

// single block: row_start scan + deterministic ballot-based species ranking
// (nslot, sp_start) -- no atomics anywhere.
__global__ void __launch_bounds__(1024) k_scan(
    const int* __restrict__ count, int* __restrict__ row_start,
    const int* __restrict__ species, int* __restrict__ nslot,
    int* __restrict__ sp_start) {
    __shared__ int lds[1024];
    __shared__ int itercnt[256 * NSPEC];
    __shared__ int spt[NSPEC];
    int t = threadIdx.x;
    int lane = t & 63;
    int w = t >> 6;
    // species pass 1: per (wave,iter) counts via ballot
#pragma unroll
    for (int j = 0; j < 16; ++j) {
        int n = w * 1024 + j * 64 + lane;
        int sp = species[n];
#pragma unroll
        for (int s = 0; s < NSPEC; ++s) {
            unsigned long long mask = __ballot(sp == s);
            if (lane == 0) itercnt[(w * 16 + j) * NSPEC + s] = (int)__popcll(mask);
        }
    }
    // row_start scan
    int base = t * 16;
    int local[16];
    int ssum = 0;
#pragma unroll
    for (int b = 0; b < 16; ++b) { local[b] = count[base + b]; ssum += local[b]; }
    lds[t] = ssum;
    __syncthreads();
    for (int off = 1; off < 1024; off <<= 1) {
        int v = (t >= off) ? lds[t - off] : 0;
        __syncthreads();
        lds[t] += v;
        __syncthreads();
    }
    int run = lds[t] - ssum;
#pragma unroll
    for (int b = 0; b < 16; ++b) { row_start[base + b] = run; run += local[b]; }
    if (t == 1023) row_start[NN] = run;
    __syncthreads();
    // species scan: exclusive over 256 iters per species
    if (t < NSPEC) {
        int r2 = 0;
        for (int i = 0; i < 256; ++i) {
            int v = itercnt[i * NSPEC + t];
            itercnt[i * NSPEC + t] = r2;
            r2 += v;
        }
        spt[t] = r2;
    }
    __syncthreads();
    if (t == 0) {
        int r2 = 0;
        for (int s = 0; s < NSPEC; ++s) { sp_start[s] = r2; r2 += spt[s]; }
        sp_start[NSPEC] = r2;
    }
    // species pass 2: nslot = iter base + rank-in-wave
#pragma unroll
    for (int j = 0; j < 16; ++j) {
        int n = w * 1024 + j * 64 + lane;
        int sp = species[n];
        int rank = 0;
#pragma unroll
        for (int s = 0; s < NSPEC; ++s) {
            unsigned long long mask = __ballot(sp == s);
            if (sp == s)
                rank = (int)__popcll(mask & ((1ull << lane) - 1ull));
        }
        nslot[n] = itercnt[(w * 16 + j) * NSPEC + sp] + rank;
    }
}

// geometry: p = row_start[r] + seg_base[g][r] + eslot[e]; also scatters ord.
// rec = [Y0..Y8, rad0..rad7, s_bits, pad, pad]
__global__ void k_geom(const float* __restrict__ pos,
                       const float* __restrict__ shifts,
                       const int* __restrict__ senders,
                       const int* __restrict__ receivers,
                       const int* __restrict__ row_start,
                       const int* __restrict__ seg_base,
                       const int* __restrict__ eslot,
                       const int* __restrict__ species,
                       const int* __restrict__ sp_start,
                       const int* __restrict__ nslot,
                       int* __restrict__ ord,
                       float* __restrict__ edgerec) {
    int e = blockIdx.x * 256 + threadIdx.x;
    if (e < NN) {
        int sp = species[e];
        ord[sp_start[sp] + nslot[e]] = e;
    }
    int s = senders[e], r = receivers[e];
    float dx = pos[r * 3 + 0] - pos[s * 3 + 0] + shifts[e * 3 + 0];
    float dy = pos[r * 3 + 1] - pos[s * 3 + 1] + shifts[e * 3 + 1];
    float dz = pos[r * 3 + 2] - pos[s * 3 + 2] + shifts[e * 3 + 2];
    float rn = sqrtf(dx * dx + dy * dy + dz * dz);
    float den = (rn > 1e-9f) ? rn : 1.0f;
    float x = dx / den, y = dy / den, z = dz / den;
    const float s3  = 1.7320508075688772f;
    const float s15 = 3.8729833462074170f;
    const float s5h = 1.1180339887498949f;
    const float s15h = 1.9364916731037085f;
    float rec[20];
    rec[0] = 1.0f;
    rec[1] = s3 * x;
    rec[2] = s3 * y;
    rec[3] = s3 * z;
    rec[4] = s15 * x * y;
    rec[5] = s15 * y * z;
    rec[6] = s5h * (3.0f * z * z - 1.0f);
    rec[7] = s15 * x * z;
    rec[8] = s15h * (x * x - y * y);
    float u = rn * 0.2f;
    float env = 0.0f;
    if (u < 1.0f) {
        float u2 = u * u;
        float u5 = u2 * u2 * u;
        env = 1.0f - 21.0f * u5 + 35.0f * u5 * u - 15.0f * u5 * u2;
    }
    float pre = 0.63245553203367587f * env / den;
#pragma unroll
    for (int nb = 1; nb <= 8; ++nb)
        rec[8 + nb] = pre * sinf((float)nb * 3.14159265358979323846f * u);
    rec[17] = __int_as_float(s);
    rec[18] = 0.f; rec[19] = 0.f;
    int p = row_start[r] + seg_base[(size_t)(e >> 11) * NN + r] + eslot[e];
    float4* o = (float4*)(edgerec + (size_t)p * 20);
#pragma unroll
    for (int i = 0; i < 5; ++i)
        o[i] = make_float4(rec[4 * i], rec[4 * i + 1], rec[4 * i + 2], rec[4 * i + 3]);
}

__device__ __forceinline__ void agg_edge(const float* __restrict__ rec, float hv,
                                         const float (&Wr)[3][8], float (&acc)[9]) {
    float R0 = 0.f, R1 = 0.f, R2 = 0.f;
#pragma unroll
    for (int b = 0; b < 8; ++b) {
        float rb = rec[9 + b];
        R0 += rb * Wr[0][b];
        R1 += rb * Wr[1][b];
        R2 += rb * Wr[2][b];
    }
    float t0 = hv * R0, t1 = hv * R1, t2 = hv * R2;
    acc[0] += t0 * rec[0];
    acc[1] += t1 * rec[1];
    acc[2] += t1 * rec[2];
    acc[3] += t1 * rec[3];
    acc[4] += t2 * rec[4];
    acc[5] += t2 * rec[5];
    acc[6] += t2 * rec[6];
    acc[7] += t2 * rec[7];
    acc[8] += t2 * rec[8];
}

// fused aggregate + mix + prod: per-wave node (readfirstlane-scalarized
// edgerec loads), acc -> private LDS xtile -> mix vs LDS W -> Bm0 only.
#define AMX_NPW 4     // nodes per wave
__global__ void __launch_bounds__(256) k_aggmix(
    const float* __restrict__ h,
    const float* __restrict__ edgerec,
    const int* __restrict__ row_start,
    const float* __restrict__ Wr_i,    // [3][8][64]
    const float* __restrict__ Wm_i,    // [3][64][64]
    const float* __restrict__ Wp_i,    // [3][3][64]
    float* __restrict__ Bm0) {
    __shared__ float Wlds[3 * 4096];   // 48 KB
    __shared__ float xtile[4][9 * 64];
    {
        float4* Wl4 = (float4*)Wlds;
        const float4* W4 = (const float4*)Wm_i;
#pragma unroll
        for (int i = 0; i < 12; ++i)
            Wl4[threadIdx.x + 256 * i] = W4[threadIdx.x + 256 * i];
    }
    __syncthreads();
    int lane = threadIdx.x & 63;
    int wid = __builtin_amdgcn_readfirstlane(threadIdx.x >> 6);
    float* xt = xtile[wid];
    float Wr[3][8];
#pragma unroll
    for (int l = 0; l < 3; ++l)
#pragma unroll
        for (int b = 0; b < 8; ++b) Wr[l][b] = Wr_i[(l * 8 + b) * 64 + lane];
    float w10 = Wp_i[0 * 64 + lane];
    float w20 = Wp_i[3 * 64 + lane];
    float w30 = Wp_i[6 * 64 + lane];
    int n0 = (blockIdx.x * 4 + wid) * AMX_NPW;
    for (int it = 0; it < AMX_NPW; ++it) {
        int n = n0 + it;
        float acc[9];
#pragma unroll
        for (int m = 0; m < 9; ++m) acc[m] = 0.f;
        int e0 = row_start[n], e1 = row_start[n + 1];
        int e = e0;
        for (; e + 2 <= e1; e += 2) {
            const float* ra = edgerec + (size_t)e * 20;
            const float* rb = ra + 20;
            int sa = __float_as_int(ra[17]);
            int sb = __float_as_int(rb[17]);
            float ha = h[(size_t)sa * 64 + lane];
            float hb = h[(size_t)sb * 64 + lane];
            agg_edge(ra, ha, Wr, acc);
            agg_edge(rb, hb, Wr, acc);
        }
        if (e < e1) {
            const float* ra = edgerec + (size_t)e * 20;
            int sa = __float_as_int(ra[17]);
            float ha = h[(size_t)sa * 64 + lane];
            agg_edge(ra, ha, Wr, acc);
        }
        const float inv_avg = 1.0f / 16.0f;
#pragma unroll
        for (int m = 0; m < 9; ++m) xt[m * 64 + lane] = acc[m] * inv_avg;
        float mix[9];
#pragma unroll
        for (int m = 0; m < 9; ++m) mix[m] = 0.f;
#pragma unroll 2
        for (int c4 = 0; c4 < 16; ++c4) {
            float4 xb[9];
#pragma unroll
            for (int m = 0; m < 9; ++m)
                xb[m] = *(const float4*)&xt[m * 64 + c4 * 4];
#pragma unroll
            for (int j = 0; j < 4; ++j) {
                int k = c4 * 4 + j;
                float wv0 = Wlds[k * 64 + lane];
                float wv1 = Wlds[4096 + k * 64 + lane];
                float wv2 = Wlds[8192 + k * 64 + lane];
                mix[0] += f4c(xb[0], j) * wv0;
                mix[1] += f4c(xb[1], j) * wv1;
                mix[2] += f4c(xb[2], j) * wv1;
                mix[3] += f4c(xb[3], j) * wv1;
                mix[4] += f4c(xb[4], j) * wv2;
                mix[5] += f4c(xb[5], j) * wv2;
                mix[6] += f4c(xb[6], j) * wv2;
                mix[7] += f4c(xb[7], j) * wv2;
                mix[8] += f4c(xb[8], j) * wv2;
            }
        }
        float A0 = mix[0];
        float inv = 0.f;
#pragma unroll
        for (int m = 0; m < 9; ++m) inv += mix[m] * mix[m];
        Bm0[(size_t)n * 64 + lane] = mix[0] * (w10 + w20 * A0 + w30 * inv);
    }
}

// l=0 self-connection + energy epilogue over species-sorted nodes.
#define RPB 32
template <int ITER>
__global__ void __launch_bounds__(256) k_sc(
    const float* __restrict__ h_in,
    const float* __restrict__ Bm0,
    float* __restrict__ h_out,
    const int* __restrict__ ord,
    const int* __restrict__ sp_start,
    const float* __restrict__ Wsc_i,     // + sp*3*4096 selects [sp][l=0]
    const float* __restrict__ W_ro0,
    const float* __restrict__ W_m1,
    const float* __restrict__ b_m1,
    const float* __restrict__ W_m2,
    float* __restrict__ out) {
    const int BPS = NN / RPB;
    int sp = blockIdx.x / BPS;
    int c  = blockIdx.x - sp * BPS;
    int base = sp_start[sp];
    int cnt  = sp_start[sp + 1] - base;
    int r0 = c * RPB;
    __shared__ float Wlds[4096];
    __shared__ float xtile[4][8 * 64];
    if (r0 < cnt) {
        const float4* W4 = (const float4*)(Wsc_i + (size_t)sp * 3 * 4096);
        float4* Wl4 = (float4*)Wlds;
#pragma unroll
        for (int i = 0; i < 4; ++i)
            Wl4[threadIdx.x + 256 * i] = W4[threadIdx.x + 256 * i];
    }
    __syncthreads();
    if (r0 >= cnt) return;
    int lane = threadIdx.x & 63;
    int wid = threadIdx.x >> 6;
    float* xt = xtile[wid];
    int rend = min(r0 + RPB, cnt);
    int q0 = r0 + wid * 8;
    if (q0 >= rend) return;
    int nd[8];
#pragma unroll
    for (int t = 0; t < 8; ++t)
        nd[t] = ord[base + min(q0 + t, rend - 1)];
    float xv[8];
#pragma unroll
    for (int t = 0; t < 8; ++t) xv[t] = h_in[(size_t)nd[t] * 64 + lane];
#pragma unroll
    for (int t = 0; t < 8; ++t) xt[t * 64 + lane] = xv[t];
    float acc[8];
#pragma unroll
    for (int t = 0; t < 8; ++t) acc[t] = 0.f;
#pragma unroll 2
    for (int c4 = 0; c4 < 16; ++c4) {
        float wv[4];
#pragma unroll
        for (int j = 0; j < 4; ++j) wv[j] = Wlds[(c4 * 4 + j) * 64 + lane];
#pragma unroll
        for (int t = 0; t < 8; ++t) {
            float4 xb = *(const float4*)&xt[t * 64 + c4 * 4];
#pragma unroll
            for (int j = 0; j < 4; ++j) acc[t] += f4c(xb, j) * wv[j];
        }
    }
    float wro = W_ro0[lane];
#pragma unroll
    for (int t = 0; t < 8; ++t) {
        if (q0 + t >= rend) break;
        int node = nd[t];
        float outv = acc[t] + Bm0[(size_t)node * 64 + lane];
        if (ITER == 0) {
            h_out[(size_t)node * 64 + lane] = outv;
            float e = wave_reduce(outv * wro);
            if (lane == 0) out[2 * node + 0] = e;
        } else {
            int hh = lane & 15;
            float tacc = b_m1[hh];
#pragma unroll
            for (int k = 0; k < 64; ++k)
                tacc += __shfl(outv, k, 64) * W_m1[k * MLPH + hh];
            float sig = 1.0f / (1.0f + expf(-tacc));
            float contrib = (lane < MLPH) ? tacc * sig * W_m2[lane] : 0.f;
            float e = wave_reduce(contrib);
            if (lane == 0) out[2 * node + 1] = e;
        }
    }
}

extern "C" void kernel_launch(void* const* d_in, const int* in_sizes, int n_in,
                              void* d_out, int out_size, void* d_ws, size_t ws_size,
                              hipStream_t stream) {
    const float* positions = (const float*)d_in[0];
    const float* shifts    = (const float*)d_in[1];
    const int*   species   = (const int*)d_in[2];
    const int*   senders   = (const int*)d_in[3];
    const int*   receivers = (const int*)d_in[4];
    const float* W_embed   = (const float*)d_in[5];
    const float* W_rad     = (const float*)d_in[6];
    const float* W_mix     = (const float*)d_in[7];
    const float* W_prod    = (const float*)d_in[8];
    const float* W_sc      = (const float*)d_in[9];
    const float* W_ro0     = (const float*)d_in[10];
    const float* W_m1      = (const float*)d_in[11];
    const float* b_m1      = (const float*)d_in[12];
    const float* W_m2      = (const float*)d_in[13];
    float* out = (float*)d_out;

    char* p = (char*)d_ws;
    float* edgerec = (float*)p; p += (size_t)NE * 20 * 4;    // 20.97 MB
    int* seg_base  = (int*)p;   p += (size_t)SEG * NN * 4;   //  8.39 MB
    float* Bm0     = (float*)p; p += (size_t)NN * KC * 4;    //  4.19 MB
    float* h0      = (float*)p; p += (size_t)NN * KC * 4;    //  4.19 MB
    float* h1      = (float*)p; p += (size_t)NN * KC * 4;    //  4.19 MB
    unsigned short* cnt16 = (unsigned short*)p; p += (size_t)SEG * NN * 2; // 4.19 MB
    int* eslot     = (int*)p; p += (size_t)NE * 4;           //  1.05 MB
    int* nslot     = (int*)p; p += (size_t)NN * 4;
    int* ord       = (int*)p; p += (size_t)NN * 4;
    int* count     = (int*)p; p += (size_t)NN * 4;
    int* row_start = (int*)p; p += (size_t)(NN + 1) * 4;
    int* sp_start  = (int*)p; p += 16 * 4;

    k_pre<<<SEG, 1024, 0, stream>>>(W_embed, species, receivers,
                                    eslot, cnt16, (float4*)h0);
    k_colscan<<<NN / 128, 128, 0, stream>>>(cnt16, seg_base, count);
    k_scan<<<1, 1024, 0, stream>>>(count, row_start, species, nslot, sp_start);
    k_geom<<<NE / 256, 256, 0, stream>>>(positions, shifts, senders, receivers,
                                         row_start, seg_base, eslot, species,
                                         sp_start, nslot, ord, edgerec);

    // ---- iteration 0 ----
    k_aggmix<<<NN / 16, 256, 0, stream>>>(h0, edgerec, row_start,
                                          W_rad + 0, W_mix + 0, W_prod + 0, Bm0);
    k_sc<0><<<NSPEC * (NN / RPB), 256, 0, stream>>>(h0, Bm0, h1, ord, sp_start,
        W_sc + 0, W_ro0, W_m1, b_m1, W_m2, out);

    // ---- iteration 1 ----
    k_aggmix<<<NN / 16, 256, 0, stream>>>(h1, edgerec, row_start,
                                          W_rad + 1536, W_mix + 12288,
                                          W_prod + 576, Bm0);
    k_sc<1><<<NSPEC * (NN / RPB), 256, 0, stream>>>(h1, Bm0, h0 /*unused*/, ord,
        sp_start, W_sc + (size_t)NSPEC * 3 * 4096, W_ro0, W_m1, b_m1, W_m2, out);
}

// Round 8
// 305.900 us; speedup vs baseline: 3.0885x; 1.1787x over previous
//
#include <hip/hip_runtime.h>

#define NN 16384      // nodes
#define NE 262144     // edges
#define NSPEC 10
#define KC 64
#define MLPH 16
#define SEG 128       // edge segments
#define EPSG 2048     // edges per segment = NE/SEG

__device__ __forceinline__ float wave_reduce(float v) {
#pragma unroll
    for (int off = 32; off > 0; off >>= 1) v += __shfl_down(v, off, 64);
    return v;
}

__device__ __forceinline__ float f4c(const float4& v, int j) {
    const float* p = &v.x;   // j compile-time after unroll
    return p[j];
}

// 128 blocks x 1024 threads. Per-block PRIVATE full histogram in LDS (64 KB):
// eslot[e] = rank of edge within (segment, receiver) -- LDS fetch-add, no
// global atomics. Segment counts dumped as u16. Also inits h0.
__global__ void __launch_bounds__(1024) k_pre(
    const float* __restrict__ W_embed,
    const int* __restrict__ species,
    const int* __restrict__ receivers,
    int* __restrict__ eslot,
    unsigned short* __restrict__ cnt16,    // [SEG][NN]
    float4* __restrict__ h04) {
    __shared__ int cntL[NN];
    int t = threadIdx.x;
#pragma unroll
    for (int i = 0; i < 16; ++i) cntL[t + 1024 * i] = 0;
    __syncthreads();
    int ebase = blockIdx.x * EPSG;
#pragma unroll
    for (int j = 0; j < EPSG / 1024; ++j) {
        int e = ebase + j * 1024 + t;
        int r = receivers[e];
        eslot[e] = atomicAdd(&cntL[r], 1);   // LDS atomic (ds_add_rtn)
    }
    // h0 init: 131072 threads x 2 float4 = NN*16
    int gt = blockIdx.x * 1024 + t;
#pragma unroll
    for (int q = 0; q < 2; ++q) {
        int idx = gt * 2 + q;
        int n = idx >> 4, w = idx & 15;
        h04[idx] = reinterpret_cast<const float4*>(W_embed + species[n] * KC)[w];
    }
    __syncthreads();
    unsigned short* o = cnt16 + (size_t)blockIdx.x * NN;
#pragma unroll
    for (int i = 0; i < 16; ++i)
        o[t + 1024 * i] = (unsigned short)cntL[t + 1024 * i];
}

// per-receiver column scan across segments: seg_base[g][r] = prefix,
// count[r] = total.  grid NN/128 x 128.
__global__ void __launch_bounds__(128) k_colscan(
    const unsigned short* __restrict__ cnt16,
    int* __restrict__ seg_base,            // [SEG][NN]
    int* __restrict__ count) {
    int r = blockIdx.x * 128 + threadIdx.x;
    int run = 0;
#pragma unroll 4
    for (int g = 0; g < SEG; ++g) {
        int c = cnt16[(size_t)g * NN + r];
        seg_base[(size_t)g * NN + r] = run;
        run += c;
    }
    count[r] = run;
}

// single block: row_start scan + deterministic ballot-based species ranking
// (nslot, sp_start) -- no atomics anywhere.
__global__ void __launch_bounds__(1024) k_scan(
    const int* __restrict__ count, int* __restrict__ row_start,
    const int* __restrict__ species, int* __restrict__ nslot,
    int* __restrict__ sp_start) {
    __shared__ int lds[1024];
    __shared__ int itercnt[256 * NSPEC];
    __shared__ int spt[NSPEC];
    int t = threadIdx.x;
    int lane = t & 63;
    int w = t >> 6;
    // species pass 1: per (wave,iter) counts via ballot
#pragma unroll
    for (int j = 0; j < 16; ++j) {
        int n = w * 1024 + j * 64 + lane;
        int sp = species[n];
#pragma unroll
        for (int s = 0; s < NSPEC; ++s) {
            unsigned long long mask = __ballot(sp == s);
            if (lane == 0) itercnt[(w * 16 + j) * NSPEC + s] = (int)__popcll(mask);
        }
    }
    // row_start scan
    int base = t * 16;
    int local[16];
    int ssum = 0;
#pragma unroll
    for (int b = 0; b < 16; ++b) { local[b] = count[base + b]; ssum += local[b]; }
    lds[t] = ssum;
    __syncthreads();
    for (int off = 1; off < 1024; off <<= 1) {
        int v = (t >= off) ? lds[t - off] : 0;
        __syncthreads();
        lds[t] += v;
        __syncthreads();
    }
    int run = lds[t] - ssum;
#pragma unroll
    for (int b = 0; b < 16; ++b) { row_start[base + b] = run; run += local[b]; }
    if (t == 1023) row_start[NN] = run;
    __syncthreads();
    // species scan: exclusive over 256 iters per species
    if (t < NSPEC) {
        int r2 = 0;
        for (int i = 0; i < 256; ++i) {
            int v = itercnt[i * NSPEC + t];
            itercnt[i * NSPEC + t] = r2;
            r2 += v;
        }
        spt[t] = r2;
    }
    __syncthreads();
    if (t == 0) {
        int r2 = 0;
        for (int s = 0; s < NSPEC; ++s) { sp_start[s] = r2; r2 += spt[s]; }
        sp_start[NSPEC] = r2;
    }
    // species pass 2: nslot = iter base + rank-in-wave
#pragma unroll
    for (int j = 0; j < 16; ++j) {
        int n = w * 1024 + j * 64 + lane;
        int sp = species[n];
        int rank = 0;
#pragma unroll
        for (int s = 0; s < NSPEC; ++s) {
            unsigned long long mask = __ballot(sp == s);
            if (sp == s)
                rank = (int)__popcll(mask & ((1ull << lane) - 1ull));
        }
        nslot[n] = itercnt[(w * 16 + j) * NSPEC + sp] + rank;
    }
}

// geometry: p = row_start[r] + seg_base[g][r] + eslot[e]; also scatters ord.
// rec = [Y0..Y8, rad0..rad7, s_bits, pad, pad]
__global__ void k_geom(const float* __restrict__ pos,
                       const float* __restrict__ shifts,
                       const int* __restrict__ senders,
                       const int* __restrict__ receivers,
                       const int* __restrict__ row_start,
                       const int* __restrict__ seg_base,
                       const int* __restrict__ eslot,
                       const int* __restrict__ species,
                       const int* __restrict__ sp_start,
                       const int* __restrict__ nslot,
                       int* __restrict__ ord,
                       float* __restrict__ edgerec) {
    int e = blockIdx.x * 256 + threadIdx.x;
    if (e < NN) {
        int sp = species[e];
        ord[sp_start[sp] + nslot[e]] = e;
    }
    int s = senders[e], r = receivers[e];
    float dx = pos[r * 3 + 0] - pos[s * 3 + 0] + shifts[e * 3 + 0];
    float dy = pos[r * 3 + 1] - pos[s * 3 + 1] + shifts[e * 3 + 1];
    float dz = pos[r * 3 + 2] - pos[s * 3 + 2] + shifts[e * 3 + 2];
    float rn = sqrtf(dx * dx + dy * dy + dz * dz);
    float den = (rn > 1e-9f) ? rn : 1.0f;
    float x = dx / den, y = dy / den, z = dz / den;
    const float s3  = 1.7320508075688772f;
    const float s15 = 3.8729833462074170f;
    const float s5h = 1.1180339887498949f;
    const float s15h = 1.9364916731037085f;
    float rec[20];
    rec[0] = 1.0f;
    rec[1] = s3 * x;
    rec[2] = s3 * y;
    rec[3] = s3 * z;
    rec[4] = s15 * x * y;
    rec[5] = s15 * y * z;
    rec[6] = s5h * (3.0f * z * z - 1.0f);
    rec[7] = s15 * x * z;
    rec[8] = s15h * (x * x - y * y);
    float u = rn * 0.2f;
    float env = 0.0f;
    if (u < 1.0f) {
        float u2 = u * u;
        float u5 = u2 * u2 * u;
        env = 1.0f - 21.0f * u5 + 35.0f * u5 * u - 15.0f * u5 * u2;
    }
    float pre = 0.63245553203367587f * env / den;
#pragma unroll
    for (int nb = 1; nb <= 8; ++nb)
        rec[8 + nb] = pre * sinf((float)nb * 3.14159265358979323846f * u);
    rec[17] = __int_as_float(s);
    rec[18] = 0.f; rec[19] = 0.f;
    int p = row_start[r] + seg_base[(size_t)(e >> 11) * NN + r] + eslot[e];
    float4* o = (float4*)(edgerec + (size_t)p * 20);
#pragma unroll
    for (int i = 0; i < 5; ++i)
        o[i] = make_float4(rec[4 * i], rec[4 * i + 1], rec[4 * i + 2], rec[4 * i + 3]);
}

__device__ __forceinline__ void agg_edge(const float* __restrict__ rec, float hv,
                                         const float (&Wr)[3][8], float (&acc)[9]) {
    float R0 = 0.f, R1 = 0.f, R2 = 0.f;
#pragma unroll
    for (int b = 0; b < 8; ++b) {
        float rb = rec[9 + b];
        R0 += rb * Wr[0][b];
        R1 += rb * Wr[1][b];
        R2 += rb * Wr[2][b];
    }
    float t0 = hv * R0, t1 = hv * R1, t2 = hv * R2;
    acc[0] += t0 * rec[0];
    acc[1] += t1 * rec[1];
    acc[2] += t1 * rec[2];
    acc[3] += t1 * rec[3];
    acc[4] += t2 * rec[4];
    acc[5] += t2 * rec[5];
    acc[6] += t2 * rec[6];
    acc[7] += t2 * rec[7];
    acc[8] += t2 * rec[8];
}

// fused aggregate + mix + prod.  512-thread blocks: 8 waves share one 48 KB
// W_mix stage; LDS = 48 + 18 = 66.25 KB -> 2 blocks/CU = 16 waves/CU (50%).
#define AMX_NPW 4     // nodes per wave
__global__ void __launch_bounds__(512) k_aggmix(
    const float* __restrict__ h,
    const float* __restrict__ edgerec,
    const int* __restrict__ row_start,
    const float* __restrict__ Wr_i,    // [3][8][64]
    const float* __restrict__ Wm_i,    // [3][64][64]
    const float* __restrict__ Wp_i,    // [3][3][64]
    float* __restrict__ Bm0) {
    __shared__ float Wlds[3 * 4096];   // 48 KB
    __shared__ float xtile[8][9 * 64]; // 18 KB
    {
        float4* Wl4 = (float4*)Wlds;
        const float4* W4 = (const float4*)Wm_i;
#pragma unroll
        for (int i = 0; i < 6; ++i)
            Wl4[threadIdx.x + 512 * i] = W4[threadIdx.x + 512 * i];
    }
    __syncthreads();
    int lane = threadIdx.x & 63;
    int wid = __builtin_amdgcn_readfirstlane(threadIdx.x >> 6);
    float* xt = xtile[wid];
    float Wr[3][8];
#pragma unroll
    for (int l = 0; l < 3; ++l)
#pragma unroll
        for (int b = 0; b < 8; ++b) Wr[l][b] = Wr_i[(l * 8 + b) * 64 + lane];
    float w10 = Wp_i[0 * 64 + lane];
    float w20 = Wp_i[3 * 64 + lane];
    float w30 = Wp_i[6 * 64 + lane];
    int n0 = (blockIdx.x * 8 + wid) * AMX_NPW;
    for (int it = 0; it < AMX_NPW; ++it) {
        int n = n0 + it;
        float acc[9];
#pragma unroll
        for (int m = 0; m < 9; ++m) acc[m] = 0.f;
        int e0 = row_start[n], e1 = row_start[n + 1];
        int e = e0;
        for (; e + 2 <= e1; e += 2) {
            const float* ra = edgerec + (size_t)e * 20;
            const float* rb = ra + 20;
            int sa = __float_as_int(ra[17]);
            int sb = __float_as_int(rb[17]);
            float ha = h[(size_t)sa * 64 + lane];
            float hb = h[(size_t)sb * 64 + lane];
            agg_edge(ra, ha, Wr, acc);
            agg_edge(rb, hb, Wr, acc);
        }
        if (e < e1) {
            const float* ra = edgerec + (size_t)e * 20;
            int sa = __float_as_int(ra[17]);
            float ha = h[(size_t)sa * 64 + lane];
            agg_edge(ra, ha, Wr, acc);
        }
        const float inv_avg = 1.0f / 16.0f;
#pragma unroll
        for (int m = 0; m < 9; ++m) xt[m * 64 + lane] = acc[m] * inv_avg;
        float mix[9];
#pragma unroll
        for (int m = 0; m < 9; ++m) mix[m] = 0.f;
#pragma unroll 2
        for (int c4 = 0; c4 < 16; ++c4) {
            float4 xb[9];
#pragma unroll
            for (int m = 0; m < 9; ++m)
                xb[m] = *(const float4*)&xt[m * 64 + c4 * 4];
#pragma unroll
            for (int j = 0; j < 4; ++j) {
                int k = c4 * 4 + j;
                float wv0 = Wlds[k * 64 + lane];
                float wv1 = Wlds[4096 + k * 64 + lane];
                float wv2 = Wlds[8192 + k * 64 + lane];
                mix[0] += f4c(xb[0], j) * wv0;
                mix[1] += f4c(xb[1], j) * wv1;
                mix[2] += f4c(xb[2], j) * wv1;
                mix[3] += f4c(xb[3], j) * wv1;
                mix[4] += f4c(xb[4], j) * wv2;
                mix[5] += f4c(xb[5], j) * wv2;
                mix[6] += f4c(xb[6], j) * wv2;
                mix[7] += f4c(xb[7], j) * wv2;
                mix[8] += f4c(xb[8], j) * wv2;
            }
        }
        float A0 = mix[0];
        float inv = 0.f;
#pragma unroll
        for (int m = 0; m < 9; ++m) inv += mix[m] * mix[m];
        Bm0[(size_t)n * 64 + lane] = mix[0] * (w10 + w20 * A0 + w30 * inv);
    }
}

// l=0 self-connection + energy epilogue over species-sorted nodes.
#define RPB 32
template <int ITER>
__global__ void __launch_bounds__(256) k_sc(
    const float* __restrict__ h_in,
    const float* __restrict__ Bm0,
    float* __restrict__ h_out,
    const int* __restrict__ ord,
    const int* __restrict__ sp_start,
    const float* __restrict__ Wsc_i,     // + sp*3*4096 selects [sp][l=0]
    const float* __restrict__ W_ro0,
    const float* __restrict__ W_m1,
    const float* __restrict__ b_m1,
    const float* __restrict__ W_m2,
    float* __restrict__ out) {
    const int BPS = NN / RPB;
    int sp = blockIdx.x / BPS;
    int c  = blockIdx.x - sp * BPS;
    int base = sp_start[sp];
    int cnt  = sp_start[sp + 1] - base;
    int r0 = c * RPB;
    __shared__ float Wlds[4096];
    __shared__ float xtile[4][8 * 64];
    if (r0 < cnt) {
        const float4* W4 = (const float4*)(Wsc_i + (size_t)sp * 3 * 4096);
        float4* Wl4 = (float4*)Wlds;
#pragma unroll
        for (int i = 0; i < 4; ++i)
            Wl4[threadIdx.x + 256 * i] = W4[threadIdx.x + 256 * i];
    }
    __syncthreads();
    if (r0 >= cnt) return;
    int lane = threadIdx.x & 63;
    int wid = threadIdx.x >> 6;
    float* xt = xtile[wid];
    int rend = min(r0 + RPB, cnt);
    int q0 = r0 + wid * 8;
    if (q0 >= rend) return;
    int nd[8];
#pragma unroll
    for (int t = 0; t < 8; ++t)
        nd[t] = ord[base + min(q0 + t, rend - 1)];
    float xv[8];
#pragma unroll
    for (int t = 0; t < 8; ++t) xv[t] = h_in[(size_t)nd[t] * 64 + lane];
#pragma unroll
    for (int t = 0; t < 8; ++t) xt[t * 64 + lane] = xv[t];
    float acc[8];
#pragma unroll
    for (int t = 0; t < 8; ++t) acc[t] = 0.f;
#pragma unroll 2
    for (int c4 = 0; c4 < 16; ++c4) {
        float wv[4];
#pragma unroll
        for (int j = 0; j < 4; ++j) wv[j] = Wlds[(c4 * 4 + j) * 64 + lane];
#pragma unroll
        for (int t = 0; t < 8; ++t) {
            float4 xb = *(const float4*)&xt[t * 64 + c4 * 4];
#pragma unroll
            for (int j = 0; j < 4; ++j) acc[t] += f4c(xb, j) * wv[j];
        }
    }
    float wro = W_ro0[lane];
#pragma unroll
    for (int t = 0; t < 8; ++t) {
        if (q0 + t >= rend) break;
        int node = nd[t];
        float outv = acc[t] + Bm0[(size_t)node * 64 + lane];
        if (ITER == 0) {
            h_out[(size_t)node * 64 + lane] = outv;
            float e = wave_reduce(outv * wro);
            if (lane == 0) out[2 * node + 0] = e;
        } else {
            int hh = lane & 15;
            float tacc = b_m1[hh];
#pragma unroll
            for (int k = 0; k < 64; ++k)
                tacc += __shfl(outv, k, 64) * W_m1[k * MLPH + hh];
            float sig = 1.0f / (1.0f + expf(-tacc));
            float contrib = (lane < MLPH) ? tacc * sig * W_m2[lane] : 0.f;
            float e = wave_reduce(contrib);
            if (lane == 0) out[2 * node + 1] = e;
        }
    }
}

extern "C" void kernel_launch(void* const* d_in, const int* in_sizes, int n_in,
                              void* d_out, int out_size, void* d_ws, size_t ws_size,
                              hipStream_t stream) {
    const float* positions = (const float*)d_in[0];
    const float* shifts    = (const float*)d_in[1];
    const int*   species   = (const int*)d_in[2];
    const int*   senders   = (const int*)d_in[3];
    const int*   receivers = (const int*)d_in[4];
    const float* W_embed   = (const float*)d_in[5];
    const float* W_rad     = (const float*)d_in[6];
    const float* W_mix     = (const float*)d_in[7];
    const float* W_prod    = (const float*)d_in[8];
    const float* W_sc      = (const float*)d_in[9];
    const float* W_ro0     = (const float*)d_in[10];
    const float* W_m1      = (const float*)d_in[11];
    const float* b_m1      = (const float*)d_in[12];
    const float* W_m2      = (const float*)d_in[13];
    float* out = (float*)d_out;

    char* p = (char*)d_ws;
    float* edgerec = (float*)p; p += (size_t)NE * 20 * 4;    // 20.97 MB
    int* seg_base  = (int*)p;   p += (size_t)SEG * NN * 4;   //  8.39 MB
    float* Bm0     = (float*)p; p += (size_t)NN * KC * 4;    //  4.19 MB
    float* h0      = (float*)p; p += (size_t)NN * KC * 4;    //  4.19 MB
    float* h1      = (float*)p; p += (size_t)NN * KC * 4;    //  4.19 MB
    unsigned short* cnt16 = (unsigned short*)p; p += (size_t)SEG * NN * 2; // 4.19 MB
    int* eslot     = (int*)p; p += (size_t)NE * 4;           //  1.05 MB
    int* nslot     = (int*)p; p += (size_t)NN * 4;
    int* ord       = (int*)p; p += (size_t)NN * 4;
    int* count     = (int*)p; p += (size_t)NN * 4;
    int* row_start = (int*)p; p += (size_t)(NN + 1) * 4;
    int* sp_start  = (int*)p; p += 16 * 4;

    k_pre<<<SEG, 1024, 0, stream>>>(W_embed, species, receivers,
                                    eslot, cnt16, (float4*)h0);
    k_colscan<<<NN / 128, 128, 0, stream>>>(cnt16, seg_base, count);
    k_scan<<<1, 1024, 0, stream>>>(count, row_start, species, nslot, sp_start);
    k_geom<<<NE / 256, 256, 0, stream>>>(positions, shifts, senders, receivers,
                                         row_start, seg_base, eslot, species,
                                         sp_start, nslot, ord, edgerec);

    // ---- iteration 0 ----
    k_aggmix<<<NN / 32, 512, 0, stream>>>(h0, edgerec, row_start,
                                          W_rad + 0, W_mix + 0, W_prod + 0, Bm0);
    k_sc<0><<<NSPEC * (NN / RPB), 256, 0, stream>>>(h0, Bm0, h1, ord, sp_start,
        W_sc + 0, W_ro0, W_m1, b_m1, W_m2, out);

    // ---- iteration 1 ----
    k_aggmix<<<NN / 32, 512, 0, stream>>>(h1, edgerec, row_start,
                                          W_rad + 1536, W_mix + 12288,
                                          W_prod + 576, Bm0);
    k_sc<1><<<NSPEC * (NN / RPB), 256, 0, stream>>>(h1, Bm0, h0 /*unused*/, ord,
        sp_start, W_sc + (size_t)NSPEC * 3 * 4096, W_ro0, W_m1, b_m1, W_m2, out);
}